// Round 1
// baseline (927.756 us; speedup 1.0000x reference)
//
#include <hip/hip_runtime.h>

#define N_NODES 50000
#define N_EDGES 800000
#define D 128

// ---------------- CSR build ----------------

__global__ __launch_bounds__(256) void count_deg(const int* __restrict__ dst,
                                                 int* __restrict__ cnt) {
  int e = blockIdx.x * blockDim.x + threadIdx.x;
  if (e < N_EDGES) atomicAdd(&cnt[dst[e]], 1);
}

__global__ __launch_bounds__(256) void compute_norm(const int* __restrict__ cnt,
                                                    float* __restrict__ norm) {
  int i = blockIdx.x * blockDim.x + threadIdx.x;
  if (i < N_NODES) {
    int d = cnt[i];
    if (d < 1) d = 1;
    norm[i] = rsqrtf((float)d);
  }
}

// single-block scan over 50000 ints (few microseconds; not hot)
__global__ __launch_bounds__(1024) void scan_rowptr(const int* __restrict__ cnt,
                                                    int* __restrict__ rowptr,
                                                    int* __restrict__ cursor) {
  __shared__ int sdata[1024];
  __shared__ int carry;
  if (threadIdx.x == 0) carry = 0;
  __syncthreads();
  for (int base = 0; base < N_NODES; base += 1024) {
    int i = base + (int)threadIdx.x;
    int v = (i < N_NODES) ? cnt[i] : 0;
    sdata[threadIdx.x] = v;
    __syncthreads();
    for (int off = 1; off < 1024; off <<= 1) {
      int t = (threadIdx.x >= (unsigned)off) ? sdata[threadIdx.x - off] : 0;
      __syncthreads();
      sdata[threadIdx.x] += t;
      __syncthreads();
    }
    int excl = carry + sdata[threadIdx.x] - v;
    if (i < N_NODES) { rowptr[i] = excl; cursor[i] = excl; }
    __syncthreads();
    if (threadIdx.x == 1023) carry += sdata[1023];
    __syncthreads();
  }
  if (threadIdx.x == 0) rowptr[N_NODES] = carry;
}

__global__ __launch_bounds__(256) void fill_csr(const int* __restrict__ src,
                                                const int* __restrict__ dst,
                                                int* __restrict__ cursor,
                                                int* __restrict__ col) {
  int e = blockIdx.x * blockDim.x + threadIdx.x;
  if (e < N_EDGES) {
    int pos = atomicAdd(&cursor[dst[e]], 1);
    col[pos] = src[e];
  }
}

// ---------------- pull-mode SpMM: out[d] = norm[d] * sum_e norm[src_e] * h[src_e] ----------------
// one wave per destination row; lane handles 2 consecutive features (float2)

__global__ __launch_bounds__(256) void spmm128(const float* __restrict__ h,
                                               const float* __restrict__ norm,
                                               const int* __restrict__ rowptr,
                                               const int* __restrict__ col,
                                               float* __restrict__ out) {
  int row = blockIdx.x * 4 + (threadIdx.x >> 6);
  if (row >= N_NODES) return;
  int lane = threadIdx.x & 63;
  int beg = rowptr[row], end = rowptr[row + 1];
  float ax = 0.f, ay = 0.f;
  for (int e = beg; e < end; ++e) {
    int s = col[e];
    float wgt = norm[s];
    float2 hv = *(const float2*)(h + (size_t)s * D + lane * 2);
    ax = fmaf(wgt, hv.x, ax);
    ay = fmaf(wgt, hv.y, ay);
  }
  float nd = norm[row];
  float2 o;
  o.x = ax * nd;
  o.y = ay * nd;
  *(float2*)(out + (size_t)row * D + lane * 2) = o;
}

// ---------------- fused two-phase GEMM ----------------
// C = relu(A1 @ B1 + A2 @ B2 + bias1 + bias2)   [K = 128 per phase, Ncols = 128]
// MODE 0: C = val          (layer-1 output h1)
// MODE 1: C = val / 3      (layer-2, k == 0)
// MODE 2: C += val / 3     (layer-2, k > 0)

template <int MODE>
__global__ __launch_bounds__(256) void gemm_fused(
    const float* __restrict__ A1, const float* __restrict__ B1,
    const float* __restrict__ A2, const float* __restrict__ B2,
    const float* __restrict__ bias1, const float* __restrict__ bias2,
    float* __restrict__ C) {
  __shared__ float As[16][68];   // [k][m], padded row stride (272 B, 16B-aligned)
  __shared__ float Bs[16][128];  // [k][j]

  int tid = threadIdx.x;
  int tx = tid & 15;   // 0..15 -> 8 output cols each
  int ty = tid >> 4;   // 0..15 -> 4 output rows each
  int m0 = blockIdx.x * 64;

  float acc[4][8];
#pragma unroll
  for (int r = 0; r < 4; ++r)
#pragma unroll
    for (int c = 0; c < 8; ++c) acc[r][c] = 0.f;

  for (int phase = 0; phase < 2; ++phase) {
    const float* A = phase ? A2 : A1;
    const float* B = phase ? B2 : B1;
    for (int k0 = 0; k0 < 128; k0 += 16) {
      // stage A tile (64 rows x 16 k), transposed into LDS
      {
        int mm = tid >> 2;        // 0..63
        int kk = (tid & 3) * 4;   // 0,4,8,12
        int gm = m0 + mm;
        float4 av = make_float4(0.f, 0.f, 0.f, 0.f);
        if (gm < N_NODES) av = *(const float4*)(A + (size_t)gm * 128 + k0 + kk);
        As[kk + 0][mm] = av.x;
        As[kk + 1][mm] = av.y;
        As[kk + 2][mm] = av.z;
        As[kk + 3][mm] = av.w;
      }
      // stage B tile (16 k x 128 j)
#pragma unroll
      for (int i = 0; i < 2; ++i) {
        int idx = tid + i * 256;  // 0..511 float4s
        int r = idx >> 5;
        int c = (idx & 31) * 4;
        *(float4*)&Bs[r][c] = *(const float4*)(B + (size_t)(k0 + r) * 128 + c);
      }
      __syncthreads();
#pragma unroll
      for (int kk = 0; kk < 16; ++kk) {
        float4 a = *(const float4*)&As[kk][ty * 4];
        float4 bA = *(const float4*)&Bs[kk][tx * 8];
        float4 bB = *(const float4*)&Bs[kk][tx * 8 + 4];
        float av[4] = {a.x, a.y, a.z, a.w};
        float bvv[8] = {bA.x, bA.y, bA.z, bA.w, bB.x, bB.y, bB.z, bB.w};
#pragma unroll
        for (int r = 0; r < 4; ++r)
#pragma unroll
          for (int c = 0; c < 8; ++c) acc[r][c] = fmaf(av[r], bvv[c], acc[r][c]);
      }
      __syncthreads();
    }
  }

  // epilogue
  int jbase = tx * 8;
  float bias[8];
#pragma unroll
  for (int c = 0; c < 8; ++c) bias[c] = bias1[jbase + c] + bias2[jbase + c];

#pragma unroll
  for (int r = 0; r < 4; ++r) {
    int m = m0 + ty * 4 + r;
    if (m < N_NODES) {
      float* p = C + (size_t)m * 128 + jbase;
      float val[8];
#pragma unroll
      for (int c = 0; c < 8; ++c) {
        float x = acc[r][c] + bias[c];
        val[c] = x > 0.f ? x : 0.f;
      }
      if (MODE == 0) {
        float4 o0 = make_float4(val[0], val[1], val[2], val[3]);
        float4 o1 = make_float4(val[4], val[5], val[6], val[7]);
        *(float4*)p = o0;
        *(float4*)(p + 4) = o1;
      } else if (MODE == 1) {
        const float s = 1.0f / 3.0f;
        float4 o0 = make_float4(val[0] * s, val[1] * s, val[2] * s, val[3] * s);
        float4 o1 = make_float4(val[4] * s, val[5] * s, val[6] * s, val[7] * s);
        *(float4*)p = o0;
        *(float4*)(p + 4) = o1;
      } else {
        const float s = 1.0f / 3.0f;
        float4 old0 = *(const float4*)p;
        float4 old1 = *(const float4*)(p + 4);
        float4 o0 = make_float4(old0.x + val[0] * s, old0.y + val[1] * s,
                                old0.z + val[2] * s, old0.w + val[3] * s);
        float4 o1 = make_float4(old1.x + val[4] * s, old1.y + val[5] * s,
                                old1.z + val[6] * s, old1.w + val[7] * s);
        *(float4*)p = o0;
        *(float4*)(p + 4) = o1;
      }
    }
  }
}

// ---------------- launcher ----------------

extern "C" void kernel_launch(void* const* d_in, const int* in_sizes, int n_in,
                              void* d_out, int out_size, void* d_ws, size_t ws_size,
                              hipStream_t stream) {
  const float* feats = (const float*)d_in[0];
  const int* src = (const int*)d_in[1];
  const int* dst = (const int*)d_in[2];
  const float* w0 = (const float*)d_in[3];
  const float* b0 = (const float*)d_in[4];
  const float* w = (const float*)d_in[5];
  const float* bw = (const float*)d_in[6];
  const float* v = (const float*)d_in[7];
  const float* bv = (const float*)d_in[8];
  float* out = (float*)d_out;

  // workspace layout (256B aligned)
  char* ws = (char*)d_ws;
  size_t off = 0;
  auto alloc = [&](size_t bytes) {
    void* p = ws + off;
    off += (bytes + 255) & ~(size_t)255;
    return p;
  };
  int* cnt = (int*)alloc(N_NODES * 4);
  float* norm = (float*)alloc(N_NODES * 4);
  int* rowptr = (int*)alloc((N_NODES + 1) * 4);
  int* cursor = (int*)alloc(N_NODES * 4);
  int* col = (int*)alloc(N_EDGES * 4);
  float* P = (float*)alloc((size_t)N_NODES * D * 4);
  float* h1 = (float*)alloc((size_t)N_NODES * D * 4);
  float* agg2 = (float*)alloc((size_t)N_NODES * D * 4);

  hipMemsetAsync(cnt, 0, N_NODES * 4, stream);

  dim3 blk256(256);
  count_deg<<<(N_EDGES + 255) / 256, blk256, 0, stream>>>(dst, cnt);
  compute_norm<<<(N_NODES + 255) / 256, blk256, 0, stream>>>(cnt, norm);
  scan_rowptr<<<1, 1024, 0, stream>>>(cnt, rowptr, cursor);
  fill_csr<<<(N_EDGES + 255) / 256, blk256, 0, stream>>>(src, dst, cursor, col);

  // P = propagate(feats)  -- shared across all k
  spmm128<<<(N_NODES + 3) / 4, blk256, 0, stream>>>(feats, norm, rowptr, col, P);

  int gblocks = (N_NODES + 63) / 64;
  for (int k = 0; k < 3; ++k) {
    const float* w0k = w0 + (size_t)k * 128 * 128;
    const float* wk = w + (size_t)k * 128 * 128;
    const float* vk = v + (size_t)k * 128 * 128;
    const float* b0k = b0 + (size_t)k * 128;
    const float* bwk = bw + (size_t)k * 128;
    const float* bvk = bv + (size_t)k * 128;

    // h1 = relu(P @ w0k + feats @ vk + b0k + bvk)
    gemm_fused<0><<<gblocks, blk256, 0, stream>>>(P, w0k, feats, vk, b0k, bvk, h1);
    // agg2 = propagate(h1)
    spmm128<<<(N_NODES + 3) / 4, blk256, 0, stream>>>(h1, norm, rowptr, col, agg2);
    // out (+)= relu(agg2 @ wk + feats @ vk + bwk + bvk) / 3
    if (k == 0)
      gemm_fused<1><<<gblocks, blk256, 0, stream>>>(agg2, wk, feats, vk, bwk, bvk, out);
    else
      gemm_fused<2><<<gblocks, blk256, 0, stream>>>(agg2, wk, feats, vk, bwk, bvk, out);
  }
}

// Round 2
// 802.289 us; speedup vs baseline: 1.1564x; 1.1564x over previous
//
#include <hip/hip_runtime.h>

#define N_NODES 50000
#define N_EDGES 800000
#define D 128
#define PLANE ((size_t)N_NODES * D)
#define NCHUNK ((N_NODES + 255) / 256)  // 196

// ---------------- CSR build ----------------

__global__ __launch_bounds__(256) void count_deg(const int* __restrict__ dst,
                                                 int* __restrict__ cnt) {
  int e = blockIdx.x * blockDim.x + threadIdx.x;
  if (e < N_EDGES) atomicAdd(&cnt[dst[e]], 1);
}

// Phase A: per-256-chunk exclusive scan + chunk totals (196 blocks, parallel)
__global__ __launch_bounds__(256) void scan_local(const int* __restrict__ cnt,
                                                  int* __restrict__ local,
                                                  int* __restrict__ partial) {
  __shared__ int s[256];
  int t = threadIdx.x;
  int i = blockIdx.x * 256 + t;
  int v = (i < N_NODES) ? cnt[i] : 0;
  s[t] = v;
  __syncthreads();
  for (int off = 1; off < 256; off <<= 1) {
    int tmp = (t >= off) ? s[t - off] : 0;
    __syncthreads();
    s[t] += tmp;
    __syncthreads();
  }
  if (i < N_NODES) local[i] = s[t] - v;
  if (t == 255) partial[blockIdx.x] = s[255];
}

// Phase B: scan the 196 chunk totals (single small block; trivial)
__global__ __launch_bounds__(256) void scan_chunks(const int* __restrict__ partial,
                                                   int* __restrict__ chunk_off,
                                                   int* __restrict__ rowptr) {
  __shared__ int s[256];
  int t = threadIdx.x;
  int v = (t < NCHUNK) ? partial[t] : 0;
  s[t] = v;
  __syncthreads();
  for (int off = 1; off < 256; off <<= 1) {
    int tmp = (t >= off) ? s[t - off] : 0;
    __syncthreads();
    s[t] += tmp;
    __syncthreads();
  }
  if (t < NCHUNK) chunk_off[t] = s[t] - v;
  if (t == 255) rowptr[N_NODES] = s[255];
}

// Phase C: rowptr/cursor/norm (196 blocks, parallel)
__global__ __launch_bounds__(256) void finalize_rows(const int* __restrict__ cnt,
                                                     const int* __restrict__ local,
                                                     const int* __restrict__ chunk_off,
                                                     int* __restrict__ rowptr,
                                                     int* __restrict__ cursor,
                                                     float* __restrict__ norm) {
  int i = blockIdx.x * 256 + threadIdx.x;
  if (i < N_NODES) {
    int r = local[i] + chunk_off[blockIdx.x];
    rowptr[i] = r;
    cursor[i] = r;
    int d = cnt[i];
    if (d < 1) d = 1;
    norm[i] = rsqrtf((float)d);
  }
}

__global__ __launch_bounds__(256) void fill_csr(const int* __restrict__ src,
                                                const int* __restrict__ dst,
                                                int* __restrict__ cursor,
                                                int* __restrict__ col) {
  int e = blockIdx.x * blockDim.x + threadIdx.x;
  if (e < N_EDGES) {
    int pos = atomicAdd(&cursor[dst[e]], 1);
    col[pos] = src[e];
  }
}

// ---------------- pull-mode SpMM over NK feature planes ----------------
// one wave per destination row; lane handles 2 consecutive features (float2)

template <int NK>
__global__ __launch_bounds__(256) void spmm(const float* __restrict__ h,
                                            const float* __restrict__ norm,
                                            const int* __restrict__ rowptr,
                                            const int* __restrict__ col,
                                            float* __restrict__ out) {
  int row = blockIdx.x * 4 + (threadIdx.x >> 6);
  if (row >= N_NODES) return;
  int lane = threadIdx.x & 63;
  int beg = rowptr[row], end = rowptr[row + 1];
  float ax[NK], ay[NK];
#pragma unroll
  for (int m = 0; m < NK; ++m) { ax[m] = 0.f; ay[m] = 0.f; }
  for (int e = beg; e < end; ++e) {
    int s = col[e];
    float wgt = norm[s];
    const float* hp = h + (size_t)s * D + lane * 2;
#pragma unroll
    for (int m = 0; m < NK; ++m) {
      float2 hv = *(const float2*)(hp + m * PLANE);
      ax[m] = fmaf(wgt, hv.x, ax[m]);
      ay[m] = fmaf(wgt, hv.y, ay[m]);
    }
  }
  float nd = norm[row];
#pragma unroll
  for (int m = 0; m < NK; ++m) {
    float2 o;
    o.x = ax[m] * nd;
    o.y = ay[m] * nd;
    *(float2*)(out + m * PLANE + (size_t)row * D + lane * 2) = o;
  }
}

// ---------------- layer-1 GEMM: h1[k] = relu(P@w0[k] + feats@v[k] + b0[k] + bv[k]) ----------------
// A tiles (P, feats) are shared across all NK stacks -> staged once, reused.

template <int NK>
__global__ __launch_bounds__(256) void gemm_h1(
    const float* __restrict__ P, const float* __restrict__ feats,
    const float* __restrict__ w0, const float* __restrict__ v,
    const float* __restrict__ b0, const float* __restrict__ bv,
    float* __restrict__ h1) {
  __shared__ float As[16][68];
  __shared__ float Bs[NK][16][128];

  int tid = threadIdx.x;
  int tx = tid & 15;
  int ty = tid >> 4;
  int m0 = blockIdx.x * 64;

  float acc[NK][4][8];
#pragma unroll
  for (int m = 0; m < NK; ++m)
#pragma unroll
    for (int r = 0; r < 4; ++r)
#pragma unroll
      for (int c = 0; c < 8; ++c) acc[m][r][c] = 0.f;

  for (int phase = 0; phase < 2; ++phase) {
    const float* A = phase ? feats : P;
    const float* B = phase ? v : w0;
    for (int k0 = 0; k0 < 128; k0 += 16) {
      {
        int mm = tid >> 2;
        int kq = (tid & 3) * 4;
        int gm = m0 + mm;
        float4 av = make_float4(0.f, 0.f, 0.f, 0.f);
        if (gm < N_NODES) av = *(const float4*)(A + (size_t)gm * 128 + k0 + kq);
        As[kq + 0][mm] = av.x;
        As[kq + 1][mm] = av.y;
        As[kq + 2][mm] = av.z;
        As[kq + 3][mm] = av.w;
      }
#pragma unroll
      for (int i = 0; i < NK * 2; ++i) {
        int idx = tid + i * 256;  // < NK*512 float4s
        int mat = idx >> 9;
        int rem = idx & 511;
        int r = rem >> 5;
        int c = (rem & 31) * 4;
        *(float4*)&Bs[mat][r][c] =
            *(const float4*)(B + (size_t)mat * 16384 + (size_t)(k0 + r) * 128 + c);
      }
      __syncthreads();
#pragma unroll
      for (int kk = 0; kk < 16; ++kk) {
        float4 a = *(const float4*)&As[kk][ty * 4];
        float av4[4] = {a.x, a.y, a.z, a.w};
#pragma unroll
        for (int m = 0; m < NK; ++m) {
          float4 bA = *(const float4*)&Bs[m][kk][tx * 8];
          float4 bB = *(const float4*)&Bs[m][kk][tx * 8 + 4];
          float bv8[8] = {bA.x, bA.y, bA.z, bA.w, bB.x, bB.y, bB.z, bB.w};
#pragma unroll
          for (int r = 0; r < 4; ++r)
#pragma unroll
            for (int c = 0; c < 8; ++c) acc[m][r][c] = fmaf(av4[r], bv8[c], acc[m][r][c]);
        }
      }
      __syncthreads();
    }
  }

  int jb = tx * 8;
#pragma unroll
  for (int m = 0; m < NK; ++m) {
    float bias[8];
#pragma unroll
    for (int c = 0; c < 8; ++c) bias[c] = b0[m * 128 + jb + c] + bv[m * 128 + jb + c];
#pragma unroll
    for (int r = 0; r < 4; ++r) {
      int row = m0 + ty * 4 + r;
      if (row < N_NODES) {
        float* p = h1 + m * PLANE + (size_t)row * 128 + jb;
        float val[8];
#pragma unroll
        for (int c = 0; c < 8; ++c) {
          float x = acc[m][r][c] + bias[c];
          val[c] = x > 0.f ? x : 0.f;
        }
        *(float4*)p = make_float4(val[0], val[1], val[2], val[3]);
        *(float4*)(p + 4) = make_float4(val[4], val[5], val[6], val[7]);
      }
    }
  }
}

// ---------------- layer-2 GEMM: out (+)= relu(agg[k]@w[k] + feats@v[k] + bw[k] + bv[k]) / 3 ----
// MODE 0: out = sum over NK stacks / 3 (single write, used with NK=3)
// MODE 1: out = val/3      (NK=1 fallback, k==0)
// MODE 2: out += val/3     (NK=1 fallback, k>0)

template <int NK, int MODE>
__global__ __launch_bounds__(256) void gemm_out(
    const float* __restrict__ agg, const float* __restrict__ feats,
    const float* __restrict__ w, const float* __restrict__ v,
    const float* __restrict__ bwp, const float* __restrict__ bvp,
    float* __restrict__ outp) {
  __shared__ float As[NK][16][68];
  __shared__ float Bs[NK][16][128];

  int tid = threadIdx.x;
  int tx = tid & 15;
  int ty = tid >> 4;
  int m0 = blockIdx.x * 64;

  float acc[NK][4][8];
#pragma unroll
  for (int m = 0; m < NK; ++m)
#pragma unroll
    for (int r = 0; r < 4; ++r)
#pragma unroll
      for (int c = 0; c < 8; ++c) acc[m][r][c] = 0.f;

  // phase 0: feats @ v[k]  (A shared across stacks)
  for (int k0 = 0; k0 < 128; k0 += 16) {
    {
      int mm = tid >> 2;
      int kq = (tid & 3) * 4;
      int gm = m0 + mm;
      float4 av = make_float4(0.f, 0.f, 0.f, 0.f);
      if (gm < N_NODES) av = *(const float4*)(feats + (size_t)gm * 128 + k0 + kq);
      As[0][kq + 0][mm] = av.x;
      As[0][kq + 1][mm] = av.y;
      As[0][kq + 2][mm] = av.z;
      As[0][kq + 3][mm] = av.w;
    }
#pragma unroll
    for (int i = 0; i < NK * 2; ++i) {
      int idx = tid + i * 256;
      int mat = idx >> 9;
      int rem = idx & 511;
      int r = rem >> 5;
      int c = (rem & 31) * 4;
      *(float4*)&Bs[mat][r][c] =
          *(const float4*)(v + (size_t)mat * 16384 + (size_t)(k0 + r) * 128 + c);
    }
    __syncthreads();
#pragma unroll
    for (int kk = 0; kk < 16; ++kk) {
      float4 a = *(const float4*)&As[0][kk][ty * 4];
      float av4[4] = {a.x, a.y, a.z, a.w};
#pragma unroll
      for (int m = 0; m < NK; ++m) {
        float4 bA = *(const float4*)&Bs[m][kk][tx * 8];
        float4 bB = *(const float4*)&Bs[m][kk][tx * 8 + 4];
        float bv8[8] = {bA.x, bA.y, bA.z, bA.w, bB.x, bB.y, bB.z, bB.w};
#pragma unroll
        for (int r = 0; r < 4; ++r)
#pragma unroll
          for (int c = 0; c < 8; ++c) acc[m][r][c] = fmaf(av4[r], bv8[c], acc[m][r][c]);
      }
    }
    __syncthreads();
  }

  // phase 1: agg[k] @ w[k]  (distinct A per stack)
  for (int k0 = 0; k0 < 128; k0 += 16) {
    {
      int mm = tid >> 2;
      int kq = (tid & 3) * 4;
      int gm = m0 + mm;
#pragma unroll
      for (int m = 0; m < NK; ++m) {
        float4 av = make_float4(0.f, 0.f, 0.f, 0.f);
        if (gm < N_NODES) av = *(const float4*)(agg + m * PLANE + (size_t)gm * 128 + k0 + kq);
        As[m][kq + 0][mm] = av.x;
        As[m][kq + 1][mm] = av.y;
        As[m][kq + 2][mm] = av.z;
        As[m][kq + 3][mm] = av.w;
      }
    }
#pragma unroll
    for (int i = 0; i < NK * 2; ++i) {
      int idx = tid + i * 256;
      int mat = idx >> 9;
      int rem = idx & 511;
      int r = rem >> 5;
      int c = (rem & 31) * 4;
      *(float4*)&Bs[mat][r][c] =
          *(const float4*)(w + (size_t)mat * 16384 + (size_t)(k0 + r) * 128 + c);
    }
    __syncthreads();
#pragma unroll
    for (int kk = 0; kk < 16; ++kk) {
#pragma unroll
      for (int m = 0; m < NK; ++m) {
        float4 a = *(const float4*)&As[m][kk][ty * 4];
        float av4[4] = {a.x, a.y, a.z, a.w};
        float4 bA = *(const float4*)&Bs[m][kk][tx * 8];
        float4 bB = *(const float4*)&Bs[m][kk][tx * 8 + 4];
        float bv8[8] = {bA.x, bA.y, bA.z, bA.w, bB.x, bB.y, bB.z, bB.w};
#pragma unroll
        for (int r = 0; r < 4; ++r)
#pragma unroll
          for (int c = 0; c < 8; ++c) acc[m][r][c] = fmaf(av4[r], bv8[c], acc[m][r][c]);
      }
    }
    __syncthreads();
  }

  int jb = tx * 8;
  float bias[NK][8];
#pragma unroll
  for (int m = 0; m < NK; ++m)
#pragma unroll
    for (int c = 0; c < 8; ++c) bias[m][c] = bwp[m * 128 + jb + c] + bvp[m * 128 + jb + c];

  const float s = 1.0f / 3.0f;
#pragma unroll
  for (int r = 0; r < 4; ++r) {
    int row = m0 + ty * 4 + r;
    if (row < N_NODES) {
      float val[8];
#pragma unroll
      for (int c = 0; c < 8; ++c) val[c] = 0.f;
#pragma unroll
      for (int m = 0; m < NK; ++m)
#pragma unroll
        for (int c = 0; c < 8; ++c) {
          float x = acc[m][r][c] + bias[m][c];
          val[c] += (x > 0.f ? x : 0.f);
        }
      float* p = outp + (size_t)row * 128 + jb;
      if (MODE == 2) {
        float4 old0 = *(const float4*)p;
        float4 old1 = *(const float4*)(p + 4);
        *(float4*)p = make_float4(old0.x + val[0] * s, old0.y + val[1] * s,
                                  old0.z + val[2] * s, old0.w + val[3] * s);
        *(float4*)(p + 4) = make_float4(old1.x + val[4] * s, old1.y + val[5] * s,
                                        old1.z + val[6] * s, old1.w + val[7] * s);
      } else {
        *(float4*)p = make_float4(val[0] * s, val[1] * s, val[2] * s, val[3] * s);
        *(float4*)(p + 4) = make_float4(val[4] * s, val[5] * s, val[6] * s, val[7] * s);
      }
    }
  }
}

// ---------------- launcher ----------------

extern "C" void kernel_launch(void* const* d_in, const int* in_sizes, int n_in,
                              void* d_out, int out_size, void* d_ws, size_t ws_size,
                              hipStream_t stream) {
  const float* feats = (const float*)d_in[0];
  const int* src = (const int*)d_in[1];
  const int* dst = (const int*)d_in[2];
  const float* w0 = (const float*)d_in[3];
  const float* b0 = (const float*)d_in[4];
  const float* w = (const float*)d_in[5];
  const float* bw = (const float*)d_in[6];
  const float* v = (const float*)d_in[7];
  const float* bv = (const float*)d_in[8];
  float* out = (float*)d_out;

  char* ws = (char*)d_ws;
  size_t off = 0;
  auto alloc = [&](size_t bytes) {
    void* p = ws + off;
    off += (bytes + 255) & ~(size_t)255;
    return p;
  };
  int* cnt = (int*)alloc(N_NODES * 4);
  int* local = (int*)alloc(N_NODES * 4);
  int* partial = (int*)alloc(NCHUNK * 4);
  int* chunk_off = (int*)alloc(NCHUNK * 4);
  float* norm = (float*)alloc(N_NODES * 4);
  int* rowptr = (int*)alloc((N_NODES + 1) * 4);
  int* cursor = (int*)alloc(N_NODES * 4);
  int* col = (int*)alloc(N_EDGES * 4);

  size_t plane_bytes = PLANE * 4;
  bool full = (ws_size - off) >= 5 * plane_bytes;

  hipMemsetAsync(cnt, 0, N_NODES * 4, stream);

  dim3 blk256(256);
  count_deg<<<(N_EDGES + 255) / 256, blk256, 0, stream>>>(dst, cnt);
  scan_local<<<NCHUNK, blk256, 0, stream>>>(cnt, local, partial);
  scan_chunks<<<1, blk256, 0, stream>>>(partial, chunk_off, rowptr);
  finalize_rows<<<NCHUNK, blk256, 0, stream>>>(cnt, local, chunk_off, rowptr, cursor, norm);
  fill_csr<<<(N_EDGES + 255) / 256, blk256, 0, stream>>>(src, dst, cursor, col);

  int sblocks = (N_NODES + 3) / 4;
  int gblocks = (N_NODES + 63) / 64;

  if (full) {
    float* h1 = (float*)alloc(3 * plane_bytes);   // planes 0..2
    float* P = (float*)alloc(plane_bytes);        // plane 3
    (void)alloc(plane_bytes);                     // plane 4 (agg planes 1,2 follow P)
    float* agg = P;                               // agg planes 0..2 = planes 3,4 (+P slot); P dead by then

    spmm<1><<<sblocks, blk256, 0, stream>>>(feats, norm, rowptr, col, P);
    gemm_h1<3><<<gblocks, blk256, 0, stream>>>(P, feats, w0, v, b0, bv, h1);
    spmm<3><<<sblocks, blk256, 0, stream>>>(h1, norm, rowptr, col, agg);
    gemm_out<3, 0><<<gblocks, blk256, 0, stream>>>(agg, feats, w, v, bw, bv, out);
  } else {
    float* P = (float*)alloc(plane_bytes);
    float* h1 = (float*)alloc(plane_bytes);
    float* agg = (float*)alloc(plane_bytes);

    spmm<1><<<sblocks, blk256, 0, stream>>>(feats, norm, rowptr, col, P);
    for (int k = 0; k < 3; ++k) {
      const float* w0k = w0 + (size_t)k * 16384;
      const float* wk = w + (size_t)k * 16384;
      const float* vk = v + (size_t)k * 16384;
      gemm_h1<1><<<gblocks, blk256, 0, stream>>>(P, feats, w0k, vk, b0 + k * 128,
                                                 bv + k * 128, h1);
      spmm<1><<<sblocks, blk256, 0, stream>>>(h1, norm, rowptr, col, agg);
      if (k == 0)
        gemm_out<1, 1><<<gblocks, blk256, 0, stream>>>(agg, feats, wk, vk, bw + k * 128,
                                                       bv + k * 128, out);
      else
        gemm_out<1, 2><<<gblocks, blk256, 0, stream>>>(agg, feats, wk, vk, bw + k * 128,
                                                       bv + k * 128, out);
    }
  }
}

// Round 3
// 544.753 us; speedup vs baseline: 1.7031x; 1.4728x over previous
//
#include <hip/hip_runtime.h>

#define N_NODES 50000
#define N_EDGES 800000
#define D 128
#define PLANE ((size_t)N_NODES * D)
#define NCHUNK ((N_NODES + 255) / 256)  // 196

typedef float f32x4 __attribute__((ext_vector_type(4)));
typedef short bf16x8 __attribute__((ext_vector_type(8)));

__device__ __forceinline__ unsigned short f2bf(float x) {
  unsigned int u = __float_as_uint(x);
  u += 0x7FFFu + ((u >> 16) & 1u);  // RNE
  return (unsigned short)(u >> 16);
}
__device__ __forceinline__ float bf2f(unsigned short h) {
  return __uint_as_float((unsigned int)h << 16);
}

// ---------------- CSR build ----------------

__global__ __launch_bounds__(256) void count_deg(const int* __restrict__ dst,
                                                 int* __restrict__ cnt) {
  int e = blockIdx.x * blockDim.x + threadIdx.x;
  if (e < N_EDGES) atomicAdd(&cnt[dst[e]], 1);
}

__global__ __launch_bounds__(256) void scan_local(const int* __restrict__ cnt,
                                                  int* __restrict__ local,
                                                  int* __restrict__ partial) {
  __shared__ int s[256];
  int t = threadIdx.x;
  int i = blockIdx.x * 256 + t;
  int v = (i < N_NODES) ? cnt[i] : 0;
  s[t] = v;
  __syncthreads();
  for (int off = 1; off < 256; off <<= 1) {
    int tmp = (t >= off) ? s[t - off] : 0;
    __syncthreads();
    s[t] += tmp;
    __syncthreads();
  }
  if (i < N_NODES) local[i] = s[t] - v;
  if (t == 255) partial[blockIdx.x] = s[255];
}

__global__ __launch_bounds__(256) void scan_chunks(const int* __restrict__ partial,
                                                   int* __restrict__ chunk_off,
                                                   int* __restrict__ rowptr) {
  __shared__ int s[256];
  int t = threadIdx.x;
  int v = (t < NCHUNK) ? partial[t] : 0;
  s[t] = v;
  __syncthreads();
  for (int off = 1; off < 256; off <<= 1) {
    int tmp = (t >= off) ? s[t - off] : 0;
    __syncthreads();
    s[t] += tmp;
    __syncthreads();
  }
  if (t < NCHUNK) chunk_off[t] = s[t] - v;
  if (t == 255) rowptr[N_NODES] = s[255];
}

__global__ __launch_bounds__(256) void finalize_rows(const int* __restrict__ cnt,
                                                     const int* __restrict__ local,
                                                     const int* __restrict__ chunk_off,
                                                     int* __restrict__ rowptr,
                                                     int* __restrict__ cursor,
                                                     float* __restrict__ norm) {
  int i = blockIdx.x * 256 + threadIdx.x;
  if (i < N_NODES) {
    int r = local[i] + chunk_off[blockIdx.x];
    rowptr[i] = r;
    cursor[i] = r;
    int d = cnt[i];
    if (d < 1) d = 1;
    norm[i] = rsqrtf((float)d);
  }
}

__global__ __launch_bounds__(256) void fill_csr(const int* __restrict__ src,
                                                const int* __restrict__ dst,
                                                int* __restrict__ cursor,
                                                int* __restrict__ col) {
  int e = blockIdx.x * blockDim.x + threadIdx.x;
  if (e < N_EDGES) {
    int pos = atomicAdd(&cursor[dst[e]], 1);
    col[pos] = src[e];
  }
}

// ---------------- fp32 -> bf16 plane convert ----------------

__global__ __launch_bounds__(256) void to_bf16(const float* __restrict__ in,
                                               unsigned short* __restrict__ out) {
  int i = blockIdx.x * 256 + threadIdx.x;  // one float4 per thread
  if ((size_t)i * 4 < PLANE) {
    float4 v = ((const float4*)in)[i];
    ushort4 o;
    o.x = f2bf(v.x);
    o.y = f2bf(v.y);
    o.z = f2bf(v.z);
    o.w = f2bf(v.w);
    ((ushort4*)out)[i] = o;
  }
}

// ---------------- weight prep: Bt[stack][n][k] bf16, K=256 = [w0|v] or [w|v] ----------------

__global__ __launch_bounds__(256) void prep_bt(const float* __restrict__ w0,
                                               const float* __restrict__ w,
                                               const float* __restrict__ v,
                                               unsigned short* __restrict__ bt_h1,
                                               unsigned short* __restrict__ bt_out) {
  int idx = blockIdx.x * 256 + threadIdx.x;  // [0, 2*3*128*256)
  if (idx >= 2 * 3 * 128 * 256) return;
  int buf = idx / 98304;
  int rem = idx - buf * 98304;
  int stack = rem / 32768;
  int rem2 = rem & 32767;
  int n = rem2 >> 8;
  int k = rem2 & 255;
  const float* srcm;
  int kk;
  if (k < 128) {
    srcm = (buf == 0) ? w0 : w;
    kk = k;
  } else {
    srcm = v;
    kk = k - 128;
  }
  float val = srcm[(size_t)stack * 16384 + (size_t)kk * 128 + n];
  unsigned short* dstb = (buf == 0) ? bt_h1 : bt_out;
  dstb[(size_t)stack * 32768 + (size_t)n * 256 + k] = f2bf(val);
}

// ---------------- pull-mode SpMM over NK bf16 planes ----------------

template <int NK>
__global__ __launch_bounds__(256) void spmm_bf(const unsigned short* __restrict__ h,
                                               const float* __restrict__ norm,
                                               const int* __restrict__ rowptr,
                                               const int* __restrict__ col,
                                               unsigned short* __restrict__ out) {
  int row = blockIdx.x * 4 + (threadIdx.x >> 6);
  if (row >= N_NODES) return;
  int lane = threadIdx.x & 63;
  int beg = rowptr[row], end = rowptr[row + 1];
  float ax[NK], ay[NK];
#pragma unroll
  for (int m = 0; m < NK; ++m) { ax[m] = 0.f; ay[m] = 0.f; }
  for (int e = beg; e < end; ++e) {
    int s = col[e];
    float wgt = norm[s];
    const unsigned short* hp = h + (size_t)s * D + lane * 2;
#pragma unroll
    for (int m = 0; m < NK; ++m) {
      ushort2 hv = *(const ushort2*)(hp + m * PLANE);
      ax[m] = fmaf(wgt, bf2f(hv.x), ax[m]);
      ay[m] = fmaf(wgt, bf2f(hv.y), ay[m]);
    }
  }
  float nd = norm[row];
#pragma unroll
  for (int m = 0; m < NK; ++m) {
    ushort2 o;
    o.x = f2bf(ax[m] * nd);
    o.y = f2bf(ay[m] * nd);
    *(ushort2*)(out + m * PLANE + (size_t)row * D + lane * 2) = o;
  }
}

// ---------------- MFMA GEMM: out[stk] = relu(A1[stk] @ B1[stk] + A2 @ B2[stk] + biases) ----------------
// K=256 fused: k<128 reads A1, k>=128 reads A2. Bt is [stack][n=128][k=256] bf16.
// No LDS: A-frag = A[m=lane&15][k=(lane>>4)*8+j] (16B load), B-frag = Bt[n=lane&15][k..] (16B load).
// Output bf16 plane per stack (relu applied, NOT scaled).

__global__ __launch_bounds__(256) void gemm_mfma(
    const unsigned short* __restrict__ A1, size_t a1_stride,
    const unsigned short* __restrict__ A2,
    const unsigned short* __restrict__ Bt,
    const float* __restrict__ bias1, const float* __restrict__ bias2,
    unsigned short* __restrict__ outp) {
  int stk = blockIdx.y;
  A1 += (size_t)stk * a1_stride;
  Bt += (size_t)stk * 32768;
  bias1 += stk * 128;
  bias2 += stk * 128;
  outp += (size_t)stk * PLANE;

  int tid = threadIdx.x;
  int lane = tid & 63;
  int wv = tid >> 6;       // wave 0..3 -> 16-row strip
  int ln15 = lane & 15;
  int g = lane >> 4;       // 0..3 -> k-subgroup of 8

  int row = blockIdx.x * 64 + wv * 16 + ln15;
  int rowc = row < N_NODES ? row : N_NODES - 1;

  const unsigned short* a1p = A1 + (size_t)rowc * 128 + g * 8;
  const unsigned short* a2p = A2 + (size_t)rowc * 128 + g * 8;
  const unsigned short* btp = Bt + (size_t)ln15 * 256 + g * 8;

  f32x4 acc[8];
#pragma unroll
  for (int nt = 0; nt < 8; ++nt) acc[nt] = (f32x4)(0.f);

#pragma unroll
  for (int s = 0; s < 8; ++s) {
    const unsigned short* ap = (s < 4) ? (a1p + s * 32) : (a2p + (s - 4) * 32);
    bf16x8 af = *(const bf16x8*)ap;
#pragma unroll
    for (int nt = 0; nt < 8; ++nt) {
      bf16x8 bfr = *(const bf16x8*)(btp + nt * 4096 + s * 32);
      acc[nt] = __builtin_amdgcn_mfma_f32_16x16x32_bf16(af, bfr, acc[nt], 0, 0, 0);
    }
  }

  // epilogue: C/D layout col=lane&15, row=(lane>>4)*4+reg  [m89-verified]
  int mbase = blockIdx.x * 64 + wv * 16 + g * 4;
#pragma unroll
  for (int nt = 0; nt < 8; ++nt) {
    int colj = nt * 16 + ln15;
    float bsum = bias1[colj] + bias2[colj];
#pragma unroll
    for (int r = 0; r < 4; ++r) {
      int m = mbase + r;
      if (m < N_NODES) {
        float x = acc[nt][r] + bsum;
        x = x > 0.f ? x : 0.f;
        outp[(size_t)m * 128 + colj] = f2bf(x);
      }
    }
  }
}

// ---------------- final reduce: out = (p0 + p1 + p2) / 3, bf16 -> fp32 ----------------

__global__ __launch_bounds__(256) void reduce3(const unsigned short* __restrict__ p,
                                               float* __restrict__ out) {
  int i = blockIdx.x * 256 + threadIdx.x;  // one 4-elem group per thread
  size_t base = (size_t)i * 4;
  if (base < PLANE) {
    ushort4 a = *(const ushort4*)(p + base);
    ushort4 b = *(const ushort4*)(p + PLANE + base);
    ushort4 c = *(const ushort4*)(p + 2 * PLANE + base);
    const float s = 1.0f / 3.0f;
    float4 o;
    o.x = (bf2f(a.x) + bf2f(b.x) + bf2f(c.x)) * s;
    o.y = (bf2f(a.y) + bf2f(b.y) + bf2f(c.y)) * s;
    o.z = (bf2f(a.z) + bf2f(b.z) + bf2f(c.z)) * s;
    o.w = (bf2f(a.w) + bf2f(b.w) + bf2f(c.w)) * s;
    *(float4*)(out + base) = o;
  }
}

// ---------------- launcher ----------------

extern "C" void kernel_launch(void* const* d_in, const int* in_sizes, int n_in,
                              void* d_out, int out_size, void* d_ws, size_t ws_size,
                              hipStream_t stream) {
  const float* feats = (const float*)d_in[0];
  const int* src = (const int*)d_in[1];
  const int* dst = (const int*)d_in[2];
  const float* w0 = (const float*)d_in[3];
  const float* b0 = (const float*)d_in[4];
  const float* w = (const float*)d_in[5];
  const float* bw = (const float*)d_in[6];
  const float* v = (const float*)d_in[7];
  const float* bv = (const float*)d_in[8];
  float* out = (float*)d_out;

  char* ws = (char*)d_ws;
  size_t off = 0;
  auto alloc = [&](size_t bytes) {
    void* p = ws + off;
    off += (bytes + 255) & ~(size_t)255;
    return p;
  };
  int* cnt = (int*)alloc(N_NODES * 4);
  int* local = (int*)alloc(N_NODES * 4);
  int* partial = (int*)alloc(NCHUNK * 4);
  int* chunk_off = (int*)alloc(NCHUNK * 4);
  float* norm = (float*)alloc(N_NODES * 4);
  int* rowptr = (int*)alloc((N_NODES + 1) * 4);
  int* cursor = (int*)alloc(N_NODES * 4);
  int* col = (int*)alloc(N_EDGES * 4);
  unsigned short* bt_h1 = (unsigned short*)alloc(3 * 32768 * 2);
  unsigned short* bt_out = (unsigned short*)alloc(3 * 32768 * 2);

  size_t pb = PLANE * 2;  // bf16 plane bytes
  unsigned short* feats_bf = (unsigned short*)alloc(pb);
  unsigned short* P_bf = (unsigned short*)alloc(pb);
  unsigned short* h1_bf = (unsigned short*)alloc(3 * pb);   // also reused as layer-2 partials
  unsigned short* agg_bf = (unsigned short*)alloc(3 * pb);

  hipMemsetAsync(cnt, 0, N_NODES * 4, stream);

  dim3 blk(256);
  count_deg<<<(N_EDGES + 255) / 256, blk, 0, stream>>>(dst, cnt);
  scan_local<<<NCHUNK, blk, 0, stream>>>(cnt, local, partial);
  scan_chunks<<<1, blk, 0, stream>>>(partial, chunk_off, rowptr);
  finalize_rows<<<NCHUNK, blk, 0, stream>>>(cnt, local, chunk_off, rowptr, cursor, norm);
  fill_csr<<<(N_EDGES + 255) / 256, blk, 0, stream>>>(src, dst, cursor, col);

  to_bf16<<<(int)((PLANE / 4 + 255) / 256), blk, 0, stream>>>(feats, feats_bf);
  prep_bt<<<(2 * 3 * 128 * 256 + 255) / 256, blk, 0, stream>>>(w0, w, v, bt_h1, bt_out);

  int sblocks = (N_NODES + 3) / 4;
  dim3 ggrid((N_NODES + 63) / 64, 3);

  // P = propagate(feats)   (shared across stacks)
  spmm_bf<1><<<sblocks, blk, 0, stream>>>(feats_bf, norm, rowptr, col, P_bf);
  // h1[k] = relu(P @ w0[k] + feats @ v[k] + b0[k] + bv[k])
  gemm_mfma<<<ggrid, blk, 0, stream>>>(P_bf, (size_t)0, feats_bf, bt_h1, b0, bv, h1_bf);
  // agg[k] = propagate(h1[k])
  spmm_bf<3><<<sblocks, blk, 0, stream>>>(h1_bf, norm, rowptr, col, agg_bf);
  // partial[k] = relu(agg[k] @ w[k] + feats @ v[k] + bw[k] + bv[k])   (reuse h1 planes)
  gemm_mfma<<<ggrid, blk, 0, stream>>>(agg_bf, PLANE, feats_bf, bt_out, bw, bv, h1_bf);
  // out = (partial[0] + partial[1] + partial[2]) / 3
  reduce3<<<(int)((PLANE / 4 + 255) / 256), blk, 0, stream>>>(h1_bf, out);
}

// Round 4
// 435.005 us; speedup vs baseline: 2.1328x; 1.2523x over previous
//
#include <hip/hip_runtime.h>

#define N_NODES 50000
#define N_EDGES 800000
#define D 128
#define PLANE ((size_t)N_NODES * D)
#define NCHUNK ((N_NODES + 255) / 256)  // 196

typedef float f32x4 __attribute__((ext_vector_type(4)));
typedef short bf16x8 __attribute__((ext_vector_type(8)));

__device__ __forceinline__ unsigned short f2bf(float x) {
  unsigned int u = __float_as_uint(x);
  u += 0x7FFFu + ((u >> 16) & 1u);  // RNE
  return (unsigned short)(u >> 16);
}
__device__ __forceinline__ float bf2f(unsigned short h) {
  return __uint_as_float((unsigned int)h << 16);
}

// ---------------- CSR build ----------------

__global__ __launch_bounds__(256) void count_deg(const int* __restrict__ dst,
                                                 int* __restrict__ cnt) {
  int e = blockIdx.x * blockDim.x + threadIdx.x;
  if (e < N_EDGES) atomicAdd(&cnt[dst[e]], 1);
}

__global__ __launch_bounds__(256) void scan_local(const int* __restrict__ cnt,
                                                  int* __restrict__ local,
                                                  int* __restrict__ partial) {
  __shared__ int s[256];
  int t = threadIdx.x;
  int i = blockIdx.x * 256 + t;
  int v = (i < N_NODES) ? cnt[i] : 0;
  s[t] = v;
  __syncthreads();
  for (int off = 1; off < 256; off <<= 1) {
    int tmp = (t >= off) ? s[t - off] : 0;
    __syncthreads();
    s[t] += tmp;
    __syncthreads();
  }
  if (i < N_NODES) local[i] = s[t] - v;
  if (t == 255) partial[blockIdx.x] = s[255];
}

__global__ __launch_bounds__(256) void scan_chunks(const int* __restrict__ partial,
                                                   int* __restrict__ chunk_off,
                                                   int* __restrict__ rowptr) {
  __shared__ int s[256];
  int t = threadIdx.x;
  int v = (t < NCHUNK) ? partial[t] : 0;
  s[t] = v;
  __syncthreads();
  for (int off = 1; off < 256; off <<= 1) {
    int tmp = (t >= off) ? s[t - off] : 0;
    __syncthreads();
    s[t] += tmp;
    __syncthreads();
  }
  if (t < NCHUNK) chunk_off[t] = s[t] - v;
  if (t == 255) rowptr[N_NODES] = s[255];
}

__global__ __launch_bounds__(256) void finalize_rows(const int* __restrict__ cnt,
                                                     const int* __restrict__ local,
                                                     const int* __restrict__ chunk_off,
                                                     int* __restrict__ rowptr,
                                                     int* __restrict__ cursor,
                                                     float* __restrict__ norm) {
  int i = blockIdx.x * 256 + threadIdx.x;
  if (i < N_NODES) {
    int r = local[i] + chunk_off[blockIdx.x];
    rowptr[i] = r;
    cursor[i] = r;
    int d = cnt[i];
    if (d < 1) d = 1;
    norm[i] = rsqrtf((float)d);
  }
}

__global__ __launch_bounds__(256) void fill_csr(const int* __restrict__ src,
                                                const int* __restrict__ dst,
                                                int* __restrict__ cursor,
                                                int* __restrict__ col) {
  int e = blockIdx.x * blockDim.x + threadIdx.x;
  if (e < N_EDGES) {
    int pos = atomicAdd(&cursor[dst[e]], 1);
    col[pos] = src[e];
  }
}

// ---------------- fp32 -> bf16 plane convert ----------------

__global__ __launch_bounds__(256) void to_bf16(const float* __restrict__ in,
                                               unsigned short* __restrict__ out) {
  int i = blockIdx.x * 256 + threadIdx.x;  // one float4 per thread
  if ((size_t)i * 4 < PLANE) {
    float4 v = ((const float4*)in)[i];
    ushort4 o;
    o.x = f2bf(v.x);
    o.y = f2bf(v.y);
    o.z = f2bf(v.z);
    o.w = f2bf(v.w);
    ((ushort4*)out)[i] = o;
  }
}

// ---------------- weight prep: Bt[stack][n][k] bf16, K=256 = [w0|v] or [w|v] ----------------

__global__ __launch_bounds__(256) void prep_bt(const float* __restrict__ w0,
                                               const float* __restrict__ w,
                                               const float* __restrict__ v,
                                               unsigned short* __restrict__ bt_h1,
                                               unsigned short* __restrict__ bt_out) {
  int idx = blockIdx.x * 256 + threadIdx.x;  // [0, 2*3*128*256)
  if (idx >= 2 * 3 * 128 * 256) return;
  int buf = idx / 98304;
  int rem = idx - buf * 98304;
  int stack = rem / 32768;
  int rem2 = rem & 32767;
  int n = rem2 >> 8;
  int k = rem2 & 255;
  const float* srcm;
  int kk;
  if (k < 128) {
    srcm = (buf == 0) ? w0 : w;
    kk = k;
  } else {
    srcm = v;
    kk = k - 128;
  }
  float val = srcm[(size_t)stack * 16384 + (size_t)kk * 128 + n];
  unsigned short* dstb = (buf == 0) ? bt_h1 : bt_out;
  dstb[(size_t)stack * 32768 + (size_t)n * 256 + k] = f2bf(val);
}

// ---------------- pull-mode SpMM over NK bf16 planes ----------------

template <int NK>
__global__ __launch_bounds__(256) void spmm_bf(const unsigned short* __restrict__ h,
                                               const float* __restrict__ norm,
                                               const int* __restrict__ rowptr,
                                               const int* __restrict__ col,
                                               unsigned short* __restrict__ out) {
  int row = blockIdx.x * 4 + (threadIdx.x >> 6);
  if (row >= N_NODES) return;
  int lane = threadIdx.x & 63;
  int beg = rowptr[row], end = rowptr[row + 1];
  float ax[NK], ay[NK];
#pragma unroll
  for (int m = 0; m < NK; ++m) { ax[m] = 0.f; ay[m] = 0.f; }
  for (int e = beg; e < end; ++e) {
    int s = col[e];
    float wgt = norm[s];
    const unsigned short* hp = h + (size_t)s * D + lane * 2;
#pragma unroll
    for (int m = 0; m < NK; ++m) {
      ushort2 hv = *(const ushort2*)(hp + m * PLANE);
      ax[m] = fmaf(wgt, bf2f(hv.x), ax[m]);
      ay[m] = fmaf(wgt, bf2f(hv.y), ay[m]);
    }
  }
  float nd = norm[row];
#pragma unroll
  for (int m = 0; m < NK; ++m) {
    ushort2 o;
    o.x = f2bf(ax[m] * nd);
    o.y = f2bf(ay[m] * nd);
    *(ushort2*)(out + m * PLANE + (size_t)row * D + lane * 2) = o;
  }
}

// ---------------- MFMA GEMM helpers ----------------
// Block: 256 threads = 4 waves, M-tile = 128 rows (wave = 32 rows as two 16-row strips).
// Full B^T for one stack (128n x 256k bf16 = 64 KB) staged in LDS once per use.
// Fragment math (m89/m120-verified): A[m=lane&15][k=(lane>>4)*8+j];
// B-frag from Bt[n=lane&15][k]; C/D col=lane&15, row=(lane>>4)*4+reg.

__device__ __forceinline__ void stage_B(unsigned short (*Bs)[256],
                                        const unsigned short* __restrict__ Btg,
                                        int tid) {
#pragma unroll
  for (int i = 0; i < 16; ++i) {
    int t = tid + i * 256;       // 0..4095 16B-chunks
    int n = t >> 5;
    int kc = t & 31;
    *(bf16x8*)&Bs[n][kc * 8] = *(const bf16x8*)(Btg + (size_t)n * 256 + kc * 8);
  }
}

// layer-1: h1[stk] = relu(A1[stk] @ B1 + A2 @ B2 + b1 + b2), bf16 out, per-stack via blockIdx.y
__global__ __launch_bounds__(256) void gemm_mfma(
    const unsigned short* __restrict__ A1, size_t a1_stride,
    const unsigned short* __restrict__ A2,
    const unsigned short* __restrict__ Bt,
    const float* __restrict__ bias1, const float* __restrict__ bias2,
    unsigned short* __restrict__ outp) {
  __shared__ unsigned short Bs[128][256];
  int stk = blockIdx.y;
  A1 += (size_t)stk * a1_stride;
  Bt += (size_t)stk * 32768;
  bias1 += stk * 128;
  bias2 += stk * 128;
  outp += (size_t)stk * PLANE;

  int tid = threadIdx.x;
  int lane = tid & 63;
  int wv = tid >> 6;
  int ln15 = lane & 15;
  int g = lane >> 4;

  stage_B(Bs, Bt, tid);
  __syncthreads();

  int m0 = blockIdx.x * 128 + wv * 32;
  int r0 = m0 + ln15;
  int r1 = m0 + 16 + ln15;
  if (r0 >= N_NODES) r0 = N_NODES - 1;
  if (r1 >= N_NODES) r1 = N_NODES - 1;
  const unsigned short* a10 = A1 + (size_t)r0 * 128 + g * 8;
  const unsigned short* a11 = A1 + (size_t)r1 * 128 + g * 8;
  const unsigned short* a20 = A2 + (size_t)r0 * 128 + g * 8;
  const unsigned short* a21 = A2 + (size_t)r1 * 128 + g * 8;

  f32x4 acc0[8], acc1[8];
#pragma unroll
  for (int nt = 0; nt < 8; ++nt) { acc0[nt] = (f32x4)(0.f); acc1[nt] = (f32x4)(0.f); }

#pragma unroll
  for (int s = 0; s < 8; ++s) {
    bf16x8 af0 = *(const bf16x8*)((s < 4) ? (a10 + s * 32) : (a20 + (s - 4) * 32));
    bf16x8 af1 = *(const bf16x8*)((s < 4) ? (a11 + s * 32) : (a21 + (s - 4) * 32));
#pragma unroll
    for (int nt = 0; nt < 8; ++nt) {
      bf16x8 bfr = *(const bf16x8*)&Bs[nt * 16 + ln15][s * 32 + g * 8];
      acc0[nt] = __builtin_amdgcn_mfma_f32_16x16x32_bf16(af0, bfr, acc0[nt], 0, 0, 0);
      acc1[nt] = __builtin_amdgcn_mfma_f32_16x16x32_bf16(af1, bfr, acc1[nt], 0, 0, 0);
    }
  }

#pragma unroll
  for (int nt = 0; nt < 8; ++nt) {
    int colj = nt * 16 + ln15;
    float bsum = bias1[colj] + bias2[colj];
#pragma unroll
    for (int r = 0; r < 4; ++r) {
      int mA = m0 + g * 4 + r;
      int mB = m0 + 16 + g * 4 + r;
      if (mA < N_NODES) {
        float x = acc0[nt][r] + bsum;
        outp[(size_t)mA * 128 + colj] = f2bf(x > 0.f ? x : 0.f);
      }
      if (mB < N_NODES) {
        float x = acc1[nt][r] + bsum;
        outp[(size_t)mB * 128 + colj] = f2bf(x > 0.f ? x : 0.f);
      }
    }
  }
}

// layer-2 fused: out = (1/3) * sum_stk relu(agg[stk] @ w[stk] + feats @ v[stk] + bw + bv), fp32 out
__global__ __launch_bounds__(256) void gemm_out_fused(
    const unsigned short* __restrict__ agg,
    const unsigned short* __restrict__ feats_bf,
    const unsigned short* __restrict__ Bt,
    const float* __restrict__ bwp, const float* __restrict__ bvp,
    float* __restrict__ outp) {
  __shared__ unsigned short Bs[128][256];

  int tid = threadIdx.x;
  int lane = tid & 63;
  int wv = tid >> 6;
  int ln15 = lane & 15;
  int g = lane >> 4;

  int m0 = blockIdx.x * 128 + wv * 32;
  int r0 = m0 + ln15;
  int r1 = m0 + 16 + ln15;
  if (r0 >= N_NODES) r0 = N_NODES - 1;
  if (r1 >= N_NODES) r1 = N_NODES - 1;
  const unsigned short* a20 = feats_bf + (size_t)r0 * 128 + g * 8;
  const unsigned short* a21 = feats_bf + (size_t)r1 * 128 + g * 8;

  f32x4 sum0[8], sum1[8];
#pragma unroll
  for (int nt = 0; nt < 8; ++nt) { sum0[nt] = (f32x4)(0.f); sum1[nt] = (f32x4)(0.f); }

  for (int stk = 0; stk < 3; ++stk) {
    __syncthreads();  // all waves done reading Bs from previous stack
    stage_B(Bs, Bt + (size_t)stk * 32768, tid);
    __syncthreads();

    const unsigned short* A1 = agg + (size_t)stk * PLANE;
    const unsigned short* a10 = A1 + (size_t)r0 * 128 + g * 8;
    const unsigned short* a11 = A1 + (size_t)r1 * 128 + g * 8;

    f32x4 acc0[8], acc1[8];
#pragma unroll
    for (int nt = 0; nt < 8; ++nt) { acc0[nt] = (f32x4)(0.f); acc1[nt] = (f32x4)(0.f); }

#pragma unroll
    for (int s = 0; s < 8; ++s) {
      bf16x8 af0 = *(const bf16x8*)((s < 4) ? (a10 + s * 32) : (a20 + (s - 4) * 32));
      bf16x8 af1 = *(const bf16x8*)((s < 4) ? (a11 + s * 32) : (a21 + (s - 4) * 32));
#pragma unroll
      for (int nt = 0; nt < 8; ++nt) {
        bf16x8 bfr = *(const bf16x8*)&Bs[nt * 16 + ln15][s * 32 + g * 8];
        acc0[nt] = __builtin_amdgcn_mfma_f32_16x16x32_bf16(af0, bfr, acc0[nt], 0, 0, 0);
        acc1[nt] = __builtin_amdgcn_mfma_f32_16x16x32_bf16(af1, bfr, acc1[nt], 0, 0, 0);
      }
    }

#pragma unroll
    for (int nt = 0; nt < 8; ++nt) {
      int colj = nt * 16 + ln15;
      float bsum = bwp[stk * 128 + colj] + bvp[stk * 128 + colj];
#pragma unroll
      for (int r = 0; r < 4; ++r) {
        float x0 = acc0[nt][r] + bsum;
        float x1 = acc1[nt][r] + bsum;
        sum0[nt][r] += (x0 > 0.f ? x0 : 0.f);
        sum1[nt][r] += (x1 > 0.f ? x1 : 0.f);
      }
    }
  }

  const float sc = 1.0f / 3.0f;
#pragma unroll
  for (int nt = 0; nt < 8; ++nt) {
    int colj = nt * 16 + ln15;
#pragma unroll
    for (int r = 0; r < 4; ++r) {
      int mA = m0 + g * 4 + r;
      int mB = m0 + 16 + g * 4 + r;
      if (mA < N_NODES) outp[(size_t)mA * 128 + colj] = sum0[nt][r] * sc;
      if (mB < N_NODES) outp[(size_t)mB * 128 + colj] = sum1[nt][r] * sc;
    }
  }
}

// ---------------- launcher ----------------

extern "C" void kernel_launch(void* const* d_in, const int* in_sizes, int n_in,
                              void* d_out, int out_size, void* d_ws, size_t ws_size,
                              hipStream_t stream) {
  const float* feats = (const float*)d_in[0];
  const int* src = (const int*)d_in[1];
  const int* dst = (const int*)d_in[2];
  const float* w0 = (const float*)d_in[3];
  const float* b0 = (const float*)d_in[4];
  const float* w = (const float*)d_in[5];
  const float* bw = (const float*)d_in[6];
  const float* v = (const float*)d_in[7];
  const float* bv = (const float*)d_in[8];
  float* out = (float*)d_out;

  char* ws = (char*)d_ws;
  size_t off = 0;
  auto alloc = [&](size_t bytes) {
    void* p = ws + off;
    off += (bytes + 255) & ~(size_t)255;
    return p;
  };
  int* cnt = (int*)alloc(N_NODES * 4);
  int* local = (int*)alloc(N_NODES * 4);
  int* partial = (int*)alloc(NCHUNK * 4);
  int* chunk_off = (int*)alloc(NCHUNK * 4);
  float* norm = (float*)alloc(N_NODES * 4);
  int* rowptr = (int*)alloc((N_NODES + 1) * 4);
  int* cursor = (int*)alloc(N_NODES * 4);
  int* col = (int*)alloc(N_EDGES * 4);
  unsigned short* bt_h1 = (unsigned short*)alloc(3 * 32768 * 2);
  unsigned short* bt_out = (unsigned short*)alloc(3 * 32768 * 2);

  size_t pb = PLANE * 2;  // bf16 plane bytes
  unsigned short* feats_bf = (unsigned short*)alloc(pb);
  unsigned short* P_bf = (unsigned short*)alloc(pb);
  unsigned short* h1_bf = (unsigned short*)alloc(3 * pb);
  unsigned short* agg_bf = (unsigned short*)alloc(3 * pb);

  hipMemsetAsync(cnt, 0, N_NODES * 4, stream);

  dim3 blk(256);
  count_deg<<<(N_EDGES + 255) / 256, blk, 0, stream>>>(dst, cnt);
  scan_local<<<NCHUNK, blk, 0, stream>>>(cnt, local, partial);
  scan_chunks<<<1, blk, 0, stream>>>(partial, chunk_off, rowptr);
  finalize_rows<<<NCHUNK, blk, 0, stream>>>(cnt, local, chunk_off, rowptr, cursor, norm);
  fill_csr<<<(N_EDGES + 255) / 256, blk, 0, stream>>>(src, dst, cursor, col);

  to_bf16<<<(int)((PLANE / 4 + 255) / 256), blk, 0, stream>>>(feats, feats_bf);
  prep_bt<<<(2 * 3 * 128 * 256 + 255) / 256, blk, 0, stream>>>(w0, w, v, bt_h1, bt_out);

  int sblocks = (N_NODES + 3) / 4;
  int mblocks = (N_NODES + 127) / 128;  // 391 -> use 392 via rounding below
  dim3 ggrid1(mblocks, 3);

  // P = propagate(feats)   (shared across stacks)
  spmm_bf<1><<<sblocks, blk, 0, stream>>>(feats_bf, norm, rowptr, col, P_bf);
  // h1[k] = relu(P @ w0[k] + feats @ v[k] + b0[k] + bv[k])
  gemm_mfma<<<ggrid1, blk, 0, stream>>>(P_bf, (size_t)0, feats_bf, bt_h1, b0, bv, h1_bf);
  // agg[k] = propagate(h1[k])
  spmm_bf<3><<<sblocks, blk, 0, stream>>>(h1_bf, norm, rowptr, col, agg_bf);
  // out = (1/3) * sum_k relu(agg[k] @ w[k] + feats @ v[k] + bw[k] + bv[k])
  gemm_out_fused<<<mblocks, blk, 0, stream>>>(agg_bf, feats_bf, bt_out, bw, bv, out);
}

// Round 5
// 372.568 us; speedup vs baseline: 2.4902x; 1.1676x over previous
//
#include <hip/hip_runtime.h>

#define N_NODES 50000
#define N_EDGES 800000
#define D 128
#define PLANE ((size_t)N_NODES * D)
#define NCHUNK ((N_NODES + 255) / 256)  // 196

typedef float f32x4 __attribute__((ext_vector_type(4)));
typedef short bf16x8 __attribute__((ext_vector_type(8)));

__device__ __forceinline__ unsigned short f2bf(float x) {
  unsigned int u = __float_as_uint(x);
  u += 0x7FFFu + ((u >> 16) & 1u);  // RNE
  return (unsigned short)(u >> 16);
}
__device__ __forceinline__ float bf2f(unsigned short h) {
  return __uint_as_float((unsigned int)h << 16);
}

// ---------------- CSR build ----------------

__global__ __launch_bounds__(256) void count_deg(const int* __restrict__ dst,
                                                 int* __restrict__ cnt) {
  int e = blockIdx.x * blockDim.x + threadIdx.x;
  if (e < N_EDGES) atomicAdd(&cnt[dst[e]], 1);
}

__global__ __launch_bounds__(256) void scan_local(const int* __restrict__ cnt,
                                                  int* __restrict__ local,
                                                  int* __restrict__ partial) {
  __shared__ int s[256];
  int t = threadIdx.x;
  int i = blockIdx.x * 256 + t;
  int v = (i < N_NODES) ? cnt[i] : 0;
  s[t] = v;
  __syncthreads();
  for (int off = 1; off < 256; off <<= 1) {
    int tmp = (t >= off) ? s[t - off] : 0;
    __syncthreads();
    s[t] += tmp;
    __syncthreads();
  }
  if (i < N_NODES) local[i] = s[t] - v;
  if (t == 255) partial[blockIdx.x] = s[255];
}

__global__ __launch_bounds__(256) void scan_chunks(const int* __restrict__ partial,
                                                   int* __restrict__ chunk_off,
                                                   int* __restrict__ rowptr) {
  __shared__ int s[256];
  int t = threadIdx.x;
  int v = (t < NCHUNK) ? partial[t] : 0;
  s[t] = v;
  __syncthreads();
  for (int off = 1; off < 256; off <<= 1) {
    int tmp = (t >= off) ? s[t - off] : 0;
    __syncthreads();
    s[t] += tmp;
    __syncthreads();
  }
  if (t < NCHUNK) chunk_off[t] = s[t] - v;
  if (t == 255) rowptr[N_NODES] = s[255];
}

__global__ __launch_bounds__(256) void finalize_rows(const int* __restrict__ cnt,
                                                     const int* __restrict__ local,
                                                     const int* __restrict__ chunk_off,
                                                     int* __restrict__ rowptr,
                                                     int* __restrict__ cursor,
                                                     float* __restrict__ norm) {
  int i = blockIdx.x * 256 + threadIdx.x;
  if (i < N_NODES) {
    int r = local[i] + chunk_off[blockIdx.x];
    rowptr[i] = r;
    cursor[i] = r;
    int d = cnt[i];
    if (d < 1) d = 1;
    norm[i] = rsqrtf((float)d);
  }
}

__global__ __launch_bounds__(256) void fill_csr(const int* __restrict__ src,
                                                const int* __restrict__ dst,
                                                int* __restrict__ cursor,
                                                int* __restrict__ col) {
  int e = blockIdx.x * blockDim.x + threadIdx.x;
  if (e < N_EDGES) {
    int pos = atomicAdd(&cursor[dst[e]], 1);
    col[pos] = src[e];
  }
}

// ---------------- fused prep: feats fp32->bf16 plane + weight transposes ----------------
// idx < PLANE/4           : convert one float4 of feats
// else                    : one weight element into Bt[buf][stack][n][k]

#define CONV_THREADS ((int)(PLANE / 4))          // 1,600,000
#define PREP_TOTAL (CONV_THREADS + 2 * 3 * 128 * 256)

__global__ __launch_bounds__(256) void prep_all(const float* __restrict__ feats,
                                                const float* __restrict__ w0,
                                                const float* __restrict__ w,
                                                const float* __restrict__ v,
                                                unsigned short* __restrict__ feats_bf,
                                                unsigned short* __restrict__ bt_h1,
                                                unsigned short* __restrict__ bt_out) {
  int idx = blockIdx.x * 256 + threadIdx.x;
  if (idx < CONV_THREADS) {
    float4 x = ((const float4*)feats)[idx];
    ushort4 o;
    o.x = f2bf(x.x);
    o.y = f2bf(x.y);
    o.z = f2bf(x.z);
    o.w = f2bf(x.w);
    ((ushort4*)feats_bf)[idx] = o;
    return;
  }
  idx -= CONV_THREADS;
  if (idx >= 2 * 3 * 128 * 256) return;
  int buf = idx / 98304;
  int rem = idx - buf * 98304;
  int stack = rem / 32768;
  int rem2 = rem & 32767;
  int n = rem2 >> 8;
  int k = rem2 & 255;
  const float* srcm;
  int kk;
  if (k < 128) {
    srcm = (buf == 0) ? w0 : w;
    kk = k;
  } else {
    srcm = v;
    kk = k - 128;
  }
  float val = srcm[(size_t)stack * 16384 + (size_t)kk * 128 + n];
  unsigned short* dstb = (buf == 0) ? bt_h1 : bt_out;
  dstb[(size_t)stack * 32768 + (size_t)n * 256 + k] = f2bf(val);
}

// ---------------- pull-mode SpMM, 4 edges/iter, 16 B/lane ----------------
// wave = one dst row. lane: sub = lane>>4 (edge slot 0..3), c16 = lane&15
// (16B chunk -> features c16*8 .. c16*8+7). Per iteration one bf16x8 load per
// plane moves 1024 B/wave covering 4 edges. Cross-sub butterfly at the end.

template <int NK>
__global__ __launch_bounds__(256) void spmm_bf(const unsigned short* __restrict__ h,
                                               const float* __restrict__ norm,
                                               const int* __restrict__ rowptr,
                                               const int* __restrict__ col,
                                               unsigned short* __restrict__ out) {
  int row = blockIdx.x * 4 + (threadIdx.x >> 6);
  if (row >= N_NODES) return;
  int lane = threadIdx.x & 63;
  int sub = lane >> 4;
  int c16 = lane & 15;
  int beg = rowptr[row], end = rowptr[row + 1];

  float acc[NK][8];
#pragma unroll
  for (int m = 0; m < NK; ++m)
#pragma unroll
    for (int j = 0; j < 8; ++j) acc[m][j] = 0.f;

#pragma unroll 2
  for (int e = beg; e < end; e += 4) {
    int eidx = e + sub;
    bool valid = eidx < end;
    int s = valid ? col[eidx] : 0;
    float wgt = valid ? norm[s] : 0.f;
    const unsigned short* hp = h + (size_t)s * D + c16 * 8;
#pragma unroll
    for (int m = 0; m < NK; ++m) {
      bf16x8 hv = *(const bf16x8*)(hp + m * PLANE);
#pragma unroll
      for (int j = 0; j < 8; ++j)
        acc[m][j] = fmaf(wgt, bf2f((unsigned short)hv[j]), acc[m][j]);
    }
  }

  // reduce across the 4 edge slots (lanes l, l^16, l^32, l^48)
#pragma unroll
  for (int m = 0; m < NK; ++m)
#pragma unroll
    for (int j = 0; j < 8; ++j) {
      float vv = acc[m][j];
      vv += __shfl_xor(vv, 16);
      vv += __shfl_xor(vv, 32);
      acc[m][j] = vv;
    }

  if (sub == 0) {
    float nd = norm[row];
#pragma unroll
    for (int m = 0; m < NK; ++m) {
      bf16x8 ov;
#pragma unroll
      for (int j = 0; j < 8; ++j) ov[j] = (short)f2bf(acc[m][j] * nd);
      *(bf16x8*)(out + m * PLANE + (size_t)row * D + c16 * 8) = ov;
    }
  }
}

// ---------------- MFMA GEMM helpers ----------------
// Block: 256 threads = 4 waves, M-tile = 128 rows (wave = 32 rows as two 16-row strips).
// Full B^T for one stack (128n x 256k bf16 = 64 KB) staged in LDS once per use.
// Fragment math (m89/m120-verified): A[m=lane&15][k=(lane>>4)*8+j];
// B-frag from Bt[n=lane&15][k]; C/D col=lane&15, row=(lane>>4)*4+reg.

__device__ __forceinline__ void stage_B(unsigned short (*Bs)[256],
                                        const unsigned short* __restrict__ Btg,
                                        int tid) {
#pragma unroll
  for (int i = 0; i < 16; ++i) {
    int t = tid + i * 256;       // 0..4095 16B-chunks
    int n = t >> 5;
    int kc = t & 31;
    *(bf16x8*)&Bs[n][kc * 8] = *(const bf16x8*)(Btg + (size_t)n * 256 + kc * 8);
  }
}

// layer-1: h1[stk] = relu(A1[stk] @ B1 + A2 @ B2 + b1 + b2), bf16 out, per-stack via blockIdx.y
__global__ __launch_bounds__(256) void gemm_mfma(
    const unsigned short* __restrict__ A1, size_t a1_stride,
    const unsigned short* __restrict__ A2,
    const unsigned short* __restrict__ Bt,
    const float* __restrict__ bias1, const float* __restrict__ bias2,
    unsigned short* __restrict__ outp) {
  __shared__ unsigned short Bs[128][256];
  int stk = blockIdx.y;
  A1 += (size_t)stk * a1_stride;
  Bt += (size_t)stk * 32768;
  bias1 += stk * 128;
  bias2 += stk * 128;
  outp += (size_t)stk * PLANE;

  int tid = threadIdx.x;
  int lane = tid & 63;
  int wv = tid >> 6;
  int ln15 = lane & 15;
  int g = lane >> 4;

  stage_B(Bs, Bt, tid);
  __syncthreads();

  int m0 = blockIdx.x * 128 + wv * 32;
  int r0 = m0 + ln15;
  int r1 = m0 + 16 + ln15;
  if (r0 >= N_NODES) r0 = N_NODES - 1;
  if (r1 >= N_NODES) r1 = N_NODES - 1;
  const unsigned short* a10 = A1 + (size_t)r0 * 128 + g * 8;
  const unsigned short* a11 = A1 + (size_t)r1 * 128 + g * 8;
  const unsigned short* a20 = A2 + (size_t)r0 * 128 + g * 8;
  const unsigned short* a21 = A2 + (size_t)r1 * 128 + g * 8;

  f32x4 acc0[8], acc1[8];
#pragma unroll
  for (int nt = 0; nt < 8; ++nt) { acc0[nt] = (f32x4)(0.f); acc1[nt] = (f32x4)(0.f); }

#pragma unroll
  for (int s = 0; s < 8; ++s) {
    bf16x8 af0 = *(const bf16x8*)((s < 4) ? (a10 + s * 32) : (a20 + (s - 4) * 32));
    bf16x8 af1 = *(const bf16x8*)((s < 4) ? (a11 + s * 32) : (a21 + (s - 4) * 32));
#pragma unroll
    for (int nt = 0; nt < 8; ++nt) {
      bf16x8 bfr = *(const bf16x8*)&Bs[nt * 16 + ln15][s * 32 + g * 8];
      acc0[nt] = __builtin_amdgcn_mfma_f32_16x16x32_bf16(af0, bfr, acc0[nt], 0, 0, 0);
      acc1[nt] = __builtin_amdgcn_mfma_f32_16x16x32_bf16(af1, bfr, acc1[nt], 0, 0, 0);
    }
  }

#pragma unroll
  for (int nt = 0; nt < 8; ++nt) {
    int colj = nt * 16 + ln15;
    float bsum = bias1[colj] + bias2[colj];
#pragma unroll
    for (int r = 0; r < 4; ++r) {
      int mA = m0 + g * 4 + r;
      int mB = m0 + 16 + g * 4 + r;
      if (mA < N_NODES) {
        float x = acc0[nt][r] + bsum;
        outp[(size_t)mA * 128 + colj] = f2bf(x > 0.f ? x : 0.f);
      }
      if (mB < N_NODES) {
        float x = acc1[nt][r] + bsum;
        outp[(size_t)mB * 128 + colj] = f2bf(x > 0.f ? x : 0.f);
      }
    }
  }
}

// layer-2 fused: out = (1/3) * sum_stk relu(agg[stk] @ w[stk] + feats @ v[stk] + bw + bv), fp32 out
__global__ __launch_bounds__(256) void gemm_out_fused(
    const unsigned short* __restrict__ agg,
    const unsigned short* __restrict__ feats_bf,
    const unsigned short* __restrict__ Bt,
    const float* __restrict__ bwp, const float* __restrict__ bvp,
    float* __restrict__ outp) {
  __shared__ unsigned short Bs[128][256];

  int tid = threadIdx.x;
  int lane = tid & 63;
  int wv = tid >> 6;
  int ln15 = lane & 15;
  int g = lane >> 4;

  int m0 = blockIdx.x * 128 + wv * 32;
  int r0 = m0 + ln15;
  int r1 = m0 + 16 + ln15;
  if (r0 >= N_NODES) r0 = N_NODES - 1;
  if (r1 >= N_NODES) r1 = N_NODES - 1;
  const unsigned short* a20 = feats_bf + (size_t)r0 * 128 + g * 8;
  const unsigned short* a21 = feats_bf + (size_t)r1 * 128 + g * 8;

  f32x4 sum0[8], sum1[8];
#pragma unroll
  for (int nt = 0; nt < 8; ++nt) { sum0[nt] = (f32x4)(0.f); sum1[nt] = (f32x4)(0.f); }

  for (int stk = 0; stk < 3; ++stk) {
    __syncthreads();  // all waves done reading Bs from previous stack
    stage_B(Bs, Bt + (size_t)stk * 32768, tid);
    __syncthreads();

    const unsigned short* A1 = agg + (size_t)stk * PLANE;
    const unsigned short* a10 = A1 + (size_t)r0 * 128 + g * 8;
    const unsigned short* a11 = A1 + (size_t)r1 * 128 + g * 8;

    f32x4 acc0[8], acc1[8];
#pragma unroll
    for (int nt = 0; nt < 8; ++nt) { acc0[nt] = (f32x4)(0.f); acc1[nt] = (f32x4)(0.f); }

#pragma unroll
    for (int s = 0; s < 8; ++s) {
      bf16x8 af0 = *(const bf16x8*)((s < 4) ? (a10 + s * 32) : (a20 + (s - 4) * 32));
      bf16x8 af1 = *(const bf16x8*)((s < 4) ? (a11 + s * 32) : (a21 + (s - 4) * 32));
#pragma unroll
      for (int nt = 0; nt < 8; ++nt) {
        bf16x8 bfr = *(const bf16x8*)&Bs[nt * 16 + ln15][s * 32 + g * 8];
        acc0[nt] = __builtin_amdgcn_mfma_f32_16x16x32_bf16(af0, bfr, acc0[nt], 0, 0, 0);
        acc1[nt] = __builtin_amdgcn_mfma_f32_16x16x32_bf16(af1, bfr, acc1[nt], 0, 0, 0);
      }
    }

#pragma unroll
    for (int nt = 0; nt < 8; ++nt) {
      int colj = nt * 16 + ln15;
      float bsum = bwp[stk * 128 + colj] + bvp[stk * 128 + colj];
#pragma unroll
      for (int r = 0; r < 4; ++r) {
        float x0 = acc0[nt][r] + bsum;
        float x1 = acc1[nt][r] + bsum;
        sum0[nt][r] += (x0 > 0.f ? x0 : 0.f);
        sum1[nt][r] += (x1 > 0.f ? x1 : 0.f);
      }
    }
  }

  const float sc = 1.0f / 3.0f;
#pragma unroll
  for (int nt = 0; nt < 8; ++nt) {
    int colj = nt * 16 + ln15;
#pragma unroll
    for (int r = 0; r < 4; ++r) {
      int mA = m0 + g * 4 + r;
      int mB = m0 + 16 + g * 4 + r;
      if (mA < N_NODES) outp[(size_t)mA * 128 + colj] = sum0[nt][r] * sc;
      if (mB < N_NODES) outp[(size_t)mB * 128 + colj] = sum1[nt][r] * sc;
    }
  }
}

// ---------------- launcher ----------------

extern "C" void kernel_launch(void* const* d_in, const int* in_sizes, int n_in,
                              void* d_out, int out_size, void* d_ws, size_t ws_size,
                              hipStream_t stream) {
  const float* feats = (const float*)d_in[0];
  const int* src = (const int*)d_in[1];
  const int* dst = (const int*)d_in[2];
  const float* w0 = (const float*)d_in[3];
  const float* b0 = (const float*)d_in[4];
  const float* w = (const float*)d_in[5];
  const float* bw = (const float*)d_in[6];
  const float* v = (const float*)d_in[7];
  const float* bv = (const float*)d_in[8];
  float* out = (float*)d_out;

  char* ws = (char*)d_ws;
  size_t off = 0;
  auto alloc = [&](size_t bytes) {
    void* p = ws + off;
    off += (bytes + 255) & ~(size_t)255;
    return p;
  };
  int* cnt = (int*)alloc(N_NODES * 4);
  int* local = (int*)alloc(N_NODES * 4);
  int* partial = (int*)alloc(NCHUNK * 4);
  int* chunk_off = (int*)alloc(NCHUNK * 4);
  float* norm = (float*)alloc(N_NODES * 4);
  int* rowptr = (int*)alloc((N_NODES + 1) * 4);
  int* cursor = (int*)alloc(N_NODES * 4);
  int* col = (int*)alloc(N_EDGES * 4);
  unsigned short* bt_h1 = (unsigned short*)alloc(3 * 32768 * 2);
  unsigned short* bt_out = (unsigned short*)alloc(3 * 32768 * 2);

  size_t pb = PLANE * 2;  // bf16 plane bytes
  unsigned short* feats_bf = (unsigned short*)alloc(pb);
  unsigned short* P_bf = (unsigned short*)alloc(pb);
  unsigned short* h1_bf = (unsigned short*)alloc(3 * pb);
  unsigned short* agg_bf = (unsigned short*)alloc(3 * pb);

  hipMemsetAsync(cnt, 0, N_NODES * 4, stream);

  dim3 blk(256);
  count_deg<<<(N_EDGES + 255) / 256, blk, 0, stream>>>(dst, cnt);
  scan_local<<<NCHUNK, blk, 0, stream>>>(cnt, local, partial);
  scan_chunks<<<1, blk, 0, stream>>>(partial, chunk_off, rowptr);
  finalize_rows<<<NCHUNK, blk, 0, stream>>>(cnt, local, chunk_off, rowptr, cursor, norm);
  fill_csr<<<(N_EDGES + 255) / 256, blk, 0, stream>>>(src, dst, cursor, col);

  prep_all<<<(PREP_TOTAL + 255) / 256, blk, 0, stream>>>(feats, w0, w, v, feats_bf,
                                                         bt_h1, bt_out);

  int sblocks = (N_NODES + 3) / 4;
  int mblocks = (N_NODES + 127) / 128;
  dim3 ggrid1(mblocks, 3);

  // P = propagate(feats)   (shared across stacks)
  spmm_bf<1><<<sblocks, blk, 0, stream>>>(feats_bf, norm, rowptr, col, P_bf);
  // h1[k] = relu(P @ w0[k] + feats @ v[k] + b0[k] + bv[k])
  gemm_mfma<<<ggrid1, blk, 0, stream>>>(P_bf, (size_t)0, feats_bf, bt_h1, b0, bv, h1_bf);
  // agg[k] = propagate(h1[k])
  spmm_bf<3><<<sblocks, blk, 0, stream>>>(h1_bf, norm, rowptr, col, agg_bf);
  // out = (1/3) * sum_k relu(agg[k] @ w[k] + feats @ v[k] + bw[k] + bv[k])
  gemm_out_fused<<<mblocks, blk, 0, stream>>>(agg_bf, feats_bf, bt_out, bw, bv, out);
}

// Round 6
// 361.321 us; speedup vs baseline: 2.5677x; 1.0311x over previous
//
#include <hip/hip_runtime.h>

#define N_NODES 50000
#define N_EDGES 800000
#define D 128
#define PLANE ((size_t)N_NODES * D)
#define NCHUNK ((N_NODES + 255) / 256)  // 196

typedef float f32x4 __attribute__((ext_vector_type(4)));
typedef short bf16x8 __attribute__((ext_vector_type(8)));

__device__ __forceinline__ unsigned short f2bf(float x) {
  unsigned int u = __float_as_uint(x);
  u += 0x7FFFu + ((u >> 16) & 1u);  // RNE
  return (unsigned short)(u >> 16);
}
__device__ __forceinline__ float bf2f(unsigned short h) {
  return __uint_as_float((unsigned int)h << 16);
}

// ---------------- CSR build ----------------

__global__ __launch_bounds__(256) void count_deg(const int* __restrict__ dst,
                                                 int* __restrict__ cnt) {
  int e = blockIdx.x * blockDim.x + threadIdx.x;
  if (e < N_EDGES) atomicAdd(&cnt[dst[e]], 1);
}

__global__ __launch_bounds__(256) void scan_local(const int* __restrict__ cnt,
                                                  int* __restrict__ local,
                                                  int* __restrict__ partial) {
  __shared__ int s[256];
  int t = threadIdx.x;
  int i = blockIdx.x * 256 + t;
  int v = (i < N_NODES) ? cnt[i] : 0;
  s[t] = v;
  __syncthreads();
  for (int off = 1; off < 256; off <<= 1) {
    int tmp = (t >= off) ? s[t - off] : 0;
    __syncthreads();
    s[t] += tmp;
    __syncthreads();
  }
  if (i < N_NODES) local[i] = s[t] - v;
  if (t == 255) partial[blockIdx.x] = s[255];
}

__global__ __launch_bounds__(256) void scan_chunks(const int* __restrict__ partial,
                                                   int* __restrict__ chunk_off,
                                                   int* __restrict__ rowptr) {
  __shared__ int s[256];
  int t = threadIdx.x;
  int v = (t < NCHUNK) ? partial[t] : 0;
  s[t] = v;
  __syncthreads();
  for (int off = 1; off < 256; off <<= 1) {
    int tmp = (t >= off) ? s[t - off] : 0;
    __syncthreads();
    s[t] += tmp;
    __syncthreads();
  }
  if (t < NCHUNK) chunk_off[t] = s[t] - v;
  if (t == 255) rowptr[N_NODES] = s[255];
}

__global__ __launch_bounds__(256) void finalize_rows(const int* __restrict__ cnt,
                                                     const int* __restrict__ local,
                                                     const int* __restrict__ chunk_off,
                                                     int* __restrict__ rowptr,
                                                     int* __restrict__ cursor,
                                                     float* __restrict__ norm) {
  int i = blockIdx.x * 256 + threadIdx.x;
  if (i < N_NODES) {
    int r = local[i] + chunk_off[blockIdx.x];
    rowptr[i] = r;
    cursor[i] = r;
    int d = cnt[i];
    if (d < 1) d = 1;
    norm[i] = rsqrtf((float)d);
  }
}

__global__ __launch_bounds__(256) void fill_csr(const int* __restrict__ src,
                                                const int* __restrict__ dst,
                                                int* __restrict__ cursor,
                                                int* __restrict__ col) {
  int e = blockIdx.x * blockDim.x + threadIdx.x;
  if (e < N_EDGES) {
    int pos = atomicAdd(&cursor[dst[e]], 1);
    col[pos] = src[e];
  }
}

// ---------------- fused prep: feats fp32->bf16 plane + weight transposes ----------------

#define CONV_THREADS ((int)(PLANE / 4))          // 1,600,000
#define PREP_TOTAL (CONV_THREADS + 2 * 3 * 128 * 256)

__global__ __launch_bounds__(256) void prep_all(const float* __restrict__ feats,
                                                const float* __restrict__ w0,
                                                const float* __restrict__ w,
                                                const float* __restrict__ v,
                                                unsigned short* __restrict__ feats_bf,
                                                unsigned short* __restrict__ bt_h1,
                                                unsigned short* __restrict__ bt_out) {
  int idx = blockIdx.x * 256 + threadIdx.x;
  if (idx < CONV_THREADS) {
    float4 x = ((const float4*)feats)[idx];
    ushort4 o;
    o.x = f2bf(x.x);
    o.y = f2bf(x.y);
    o.z = f2bf(x.z);
    o.w = f2bf(x.w);
    ((ushort4*)feats_bf)[idx] = o;
    return;
  }
  idx -= CONV_THREADS;
  if (idx >= 2 * 3 * 128 * 256) return;
  int buf = idx / 98304;
  int rem = idx - buf * 98304;
  int stack = rem / 32768;
  int rem2 = rem & 32767;
  int n = rem2 >> 8;
  int k = rem2 & 255;
  const float* srcm;
  int kk;
  if (k < 128) {
    srcm = (buf == 0) ? w0 : w;
    kk = k;
  } else {
    srcm = v;
    kk = k - 128;
  }
  float val = srcm[(size_t)stack * 16384 + (size_t)kk * 128 + n];
  unsigned short* dstb = (buf == 0) ? bt_h1 : bt_out;
  dstb[(size_t)stack * 32768 + (size_t)n * 256 + k] = f2bf(val);
}

// ---------------- pull-mode SpMM, 4 edges/iter x unroll 4, 16 B/lane ----------------

template <int NK>
__global__ __launch_bounds__(256) void spmm_bf(const unsigned short* __restrict__ h,
                                               const float* __restrict__ norm,
                                               const int* __restrict__ rowptr,
                                               const int* __restrict__ col,
                                               unsigned short* __restrict__ out) {
  int row = blockIdx.x * 4 + (threadIdx.x >> 6);
  if (row >= N_NODES) return;
  int lane = threadIdx.x & 63;
  int sub = lane >> 4;
  int c16 = lane & 15;
  int beg = rowptr[row], end = rowptr[row + 1];

  float acc[NK][8];
#pragma unroll
  for (int m = 0; m < NK; ++m)
#pragma unroll
    for (int j = 0; j < 8; ++j) acc[m][j] = 0.f;

#pragma unroll 4
  for (int e = beg; e < end; e += 4) {
    int eidx = e + sub;
    bool valid = eidx < end;
    int s = valid ? col[eidx] : 0;
    float wgt = valid ? norm[s] : 0.f;
    const unsigned short* hp = h + (size_t)s * D + c16 * 8;
#pragma unroll
    for (int m = 0; m < NK; ++m) {
      bf16x8 hv = *(const bf16x8*)(hp + m * PLANE);
#pragma unroll
      for (int j = 0; j < 8; ++j)
        acc[m][j] = fmaf(wgt, bf2f((unsigned short)hv[j]), acc[m][j]);
    }
  }

#pragma unroll
  for (int m = 0; m < NK; ++m)
#pragma unroll
    for (int j = 0; j < 8; ++j) {
      float vv = acc[m][j];
      vv += __shfl_xor(vv, 16);
      vv += __shfl_xor(vv, 32);
      acc[m][j] = vv;
    }

  if (sub == 0) {
    float nd = norm[row];
#pragma unroll
    for (int m = 0; m < NK; ++m) {
      bf16x8 ov;
#pragma unroll
      for (int j = 0; j < 8; ++j) ov[j] = (short)f2bf(acc[m][j] * nd);
      *(bf16x8*)(out + m * PLANE + (size_t)row * D + c16 * 8) = ov;
    }
  }
}

// ---------------- MFMA GEMM ----------------
// Block: 256 threads = 4 waves, M-tile 128 rows, N-tile 64 cols (blockIdx.y half).
// B half-tile (64n x 256k bf16 = 32 KB) in LDS, XOR-swizzled:
//   chunk c (8 bf16) of row n stored at chunk c ^ (n & 31).
//   -> fragment reads (lanes differ in n by 1) spread across bank quads: 2-way max.
// Fragments (m89/m120-verified): A[m=lane&15][k=(lane>>4)*8+j];
// B-frag = Bt[n=lane&15][k..]; C/D col=lane&15, row=(lane>>4)*4+reg.

__device__ __forceinline__ void stage_B64(unsigned short (*Bs)[256],
                                          const unsigned short* __restrict__ Btg,
                                          int nh, int tid) {
#pragma unroll
  for (int i = 0; i < 8; ++i) {
    int t = tid + i * 256;       // 0..2047 16B-chunks
    int n = t >> 5;              // 0..63
    int kc = t & 31;
    int kcs = kc ^ (n & 31);     // swizzle
    *(bf16x8*)&Bs[n][kcs * 8] = *(const bf16x8*)(Btg + (size_t)(nh + n) * 256 + kc * 8);
  }
}

__device__ __forceinline__ bf16x8 read_B64(const unsigned short (*Bs)[256], int n,
                                           int chunk) {
  return *(const bf16x8*)&Bs[n][(chunk ^ (n & 31)) * 8];
}

// layer-1: h1[stk] = relu(A1[stk] @ B1 + A2 @ B2 + b1 + b2), bf16 out
__global__ __launch_bounds__(256) void gemm_mfma(
    const unsigned short* __restrict__ A1, size_t a1_stride,
    const unsigned short* __restrict__ A2,
    const unsigned short* __restrict__ Bt,
    const float* __restrict__ bias1, const float* __restrict__ bias2,
    unsigned short* __restrict__ outp) {
  __shared__ unsigned short Bs[64][256];
  int stk = blockIdx.z;
  int nh = blockIdx.y * 64;
  A1 += (size_t)stk * a1_stride;
  Bt += (size_t)stk * 32768;
  bias1 += stk * 128;
  bias2 += stk * 128;
  outp += (size_t)stk * PLANE;

  int tid = threadIdx.x;
  int lane = tid & 63;
  int wv = tid >> 6;
  int ln15 = lane & 15;
  int g = lane >> 4;

  stage_B64(Bs, Bt, nh, tid);
  __syncthreads();

  int m0 = blockIdx.x * 128 + wv * 32;
  int r0 = m0 + ln15;
  int r1 = m0 + 16 + ln15;
  if (r0 >= N_NODES) r0 = N_NODES - 1;
  if (r1 >= N_NODES) r1 = N_NODES - 1;
  const unsigned short* a10 = A1 + (size_t)r0 * 128 + g * 8;
  const unsigned short* a11 = A1 + (size_t)r1 * 128 + g * 8;
  const unsigned short* a20 = A2 + (size_t)r0 * 128 + g * 8;
  const unsigned short* a21 = A2 + (size_t)r1 * 128 + g * 8;

  f32x4 acc0[4], acc1[4];
#pragma unroll
  for (int nt = 0; nt < 4; ++nt) { acc0[nt] = (f32x4)(0.f); acc1[nt] = (f32x4)(0.f); }

#pragma unroll
  for (int s = 0; s < 8; ++s) {
    bf16x8 af0 = *(const bf16x8*)((s < 4) ? (a10 + s * 32) : (a20 + (s - 4) * 32));
    bf16x8 af1 = *(const bf16x8*)((s < 4) ? (a11 + s * 32) : (a21 + (s - 4) * 32));
#pragma unroll
    for (int nt = 0; nt < 4; ++nt) {
      bf16x8 bfr = read_B64(Bs, nt * 16 + ln15, s * 4 + g);
      acc0[nt] = __builtin_amdgcn_mfma_f32_16x16x32_bf16(af0, bfr, acc0[nt], 0, 0, 0);
      acc1[nt] = __builtin_amdgcn_mfma_f32_16x16x32_bf16(af1, bfr, acc1[nt], 0, 0, 0);
    }
  }

#pragma unroll
  for (int nt = 0; nt < 4; ++nt) {
    int colj = nh + nt * 16 + ln15;
    float bsum = bias1[colj] + bias2[colj];
#pragma unroll
    for (int r = 0; r < 4; ++r) {
      int mA = m0 + g * 4 + r;
      int mB = m0 + 16 + g * 4 + r;
      if (mA < N_NODES) {
        float x = acc0[nt][r] + bsum;
        outp[(size_t)mA * 128 + colj] = f2bf(x > 0.f ? x : 0.f);
      }
      if (mB < N_NODES) {
        float x = acc1[nt][r] + bsum;
        outp[(size_t)mB * 128 + colj] = f2bf(x > 0.f ? x : 0.f);
      }
    }
  }
}

// layer-2 fused: out = (1/3) * sum_stk relu(agg[stk] @ w[stk] + feats @ v[stk] + bw + bv), fp32
__global__ __launch_bounds__(256) void gemm_out_fused(
    const unsigned short* __restrict__ agg,
    const unsigned short* __restrict__ feats_bf,
    const unsigned short* __restrict__ Bt,
    const float* __restrict__ bwp, const float* __restrict__ bvp,
    float* __restrict__ outp) {
  __shared__ unsigned short Bs[64][256];
  int nh = blockIdx.y * 64;

  int tid = threadIdx.x;
  int lane = tid & 63;
  int wv = tid >> 6;
  int ln15 = lane & 15;
  int g = lane >> 4;

  int m0 = blockIdx.x * 128 + wv * 32;
  int r0 = m0 + ln15;
  int r1 = m0 + 16 + ln15;
  if (r0 >= N_NODES) r0 = N_NODES - 1;
  if (r1 >= N_NODES) r1 = N_NODES - 1;
  const unsigned short* a20 = feats_bf + (size_t)r0 * 128 + g * 8;
  const unsigned short* a21 = feats_bf + (size_t)r1 * 128 + g * 8;

  f32x4 sum0[4], sum1[4];
#pragma unroll
  for (int nt = 0; nt < 4; ++nt) { sum0[nt] = (f32x4)(0.f); sum1[nt] = (f32x4)(0.f); }

  for (int stk = 0; stk < 3; ++stk) {
    __syncthreads();
    stage_B64(Bs, Bt + (size_t)stk * 32768, nh, tid);
    __syncthreads();

    const unsigned short* A1 = agg + (size_t)stk * PLANE;
    const unsigned short* a10 = A1 + (size_t)r0 * 128 + g * 8;
    const unsigned short* a11 = A1 + (size_t)r1 * 128 + g * 8;

    f32x4 acc0[4], acc1[4];
#pragma unroll
    for (int nt = 0; nt < 4; ++nt) { acc0[nt] = (f32x4)(0.f); acc1[nt] = (f32x4)(0.f); }

#pragma unroll
    for (int s = 0; s < 8; ++s) {
      bf16x8 af0 = *(const bf16x8*)((s < 4) ? (a10 + s * 32) : (a20 + (s - 4) * 32));
      bf16x8 af1 = *(const bf16x8*)((s < 4) ? (a11 + s * 32) : (a21 + (s - 4) * 32));
#pragma unroll
      for (int nt = 0; nt < 4; ++nt) {
        bf16x8 bfr = read_B64(Bs, nt * 16 + ln15, s * 4 + g);
        acc0[nt] = __builtin_amdgcn_mfma_f32_16x16x32_bf16(af0, bfr, acc0[nt], 0, 0, 0);
        acc1[nt] = __builtin_amdgcn_mfma_f32_16x16x32_bf16(af1, bfr, acc1[nt], 0, 0, 0);
      }
    }

#pragma unroll
    for (int nt = 0; nt < 4; ++nt) {
      int colj = nh + nt * 16 + ln15;
      float bsum = bwp[stk * 128 + colj] + bvp[stk * 128 + colj];
#pragma unroll
      for (int r = 0; r < 4; ++r) {
        float x0 = acc0[nt][r] + bsum;
        float x1 = acc1[nt][r] + bsum;
        sum0[nt][r] += (x0 > 0.f ? x0 : 0.f);
        sum1[nt][r] += (x1 > 0.f ? x1 : 0.f);
      }
    }
  }

  const float sc = 1.0f / 3.0f;
#pragma unroll
  for (int nt = 0; nt < 4; ++nt) {
    int colj = nh + nt * 16 + ln15;
#pragma unroll
    for (int r = 0; r < 4; ++r) {
      int mA = m0 + g * 4 + r;
      int mB = m0 + 16 + g * 4 + r;
      if (mA < N_NODES) outp[(size_t)mA * 128 + colj] = sum0[nt][r] * sc;
      if (mB < N_NODES) outp[(size_t)mB * 128 + colj] = sum1[nt][r] * sc;
    }
  }
}

// ---------------- launcher ----------------

extern "C" void kernel_launch(void* const* d_in, const int* in_sizes, int n_in,
                              void* d_out, int out_size, void* d_ws, size_t ws_size,
                              hipStream_t stream) {
  const float* feats = (const float*)d_in[0];
  const int* src = (const int*)d_in[1];
  const int* dst = (const int*)d_in[2];
  const float* w0 = (const float*)d_in[3];
  const float* b0 = (const float*)d_in[4];
  const float* w = (const float*)d_in[5];
  const float* bw = (const float*)d_in[6];
  const float* v = (const float*)d_in[7];
  const float* bv = (const float*)d_in[8];
  float* out = (float*)d_out;

  char* ws = (char*)d_ws;
  size_t off = 0;
  auto alloc = [&](size_t bytes) {
    void* p = ws + off;
    off += (bytes + 255) & ~(size_t)255;
    return p;
  };
  int* cnt = (int*)alloc(N_NODES * 4);
  int* local = (int*)alloc(N_NODES * 4);
  int* partial = (int*)alloc(NCHUNK * 4);
  int* chunk_off = (int*)alloc(NCHUNK * 4);
  float* norm = (float*)alloc(N_NODES * 4);
  int* rowptr = (int*)alloc((N_NODES + 1) * 4);
  int* cursor = (int*)alloc(N_NODES * 4);
  int* col = (int*)alloc(N_EDGES * 4);
  unsigned short* bt_h1 = (unsigned short*)alloc(3 * 32768 * 2);
  unsigned short* bt_out = (unsigned short*)alloc(3 * 32768 * 2);

  size_t pb = PLANE * 2;  // bf16 plane bytes
  unsigned short* feats_bf = (unsigned short*)alloc(pb);
  unsigned short* P_bf = (unsigned short*)alloc(pb);
  unsigned short* h1_bf = (unsigned short*)alloc(3 * pb);
  unsigned short* agg_bf = (unsigned short*)alloc(3 * pb);

  hipMemsetAsync(cnt, 0, N_NODES * 4, stream);

  dim3 blk(256);
  count_deg<<<(N_EDGES + 255) / 256, blk, 0, stream>>>(dst, cnt);
  scan_local<<<NCHUNK, blk, 0, stream>>>(cnt, local, partial);
  scan_chunks<<<1, blk, 0, stream>>>(partial, chunk_off, rowptr);
  finalize_rows<<<NCHUNK, blk, 0, stream>>>(cnt, local, chunk_off, rowptr, cursor, norm);
  fill_csr<<<(N_EDGES + 255) / 256, blk, 0, stream>>>(src, dst, cursor, col);

  prep_all<<<(PREP_TOTAL + 255) / 256, blk, 0, stream>>>(feats, w0, w, v, feats_bf,
                                                         bt_h1, bt_out);

  int sblocks = (N_NODES + 3) / 4;
  int mblocks = (N_NODES + 127) / 128;
  dim3 ggrid1(mblocks, 2, 3);  // x: M-tile, y: N-half, z: stack
  dim3 ggrid2(mblocks, 2);     // x: M-tile, y: N-half (stacks looped in-kernel)

  // P = propagate(feats)   (shared across stacks)
  spmm_bf<1><<<sblocks, blk, 0, stream>>>(feats_bf, norm, rowptr, col, P_bf);
  // h1[k] = relu(P @ w0[k] + feats @ v[k] + b0[k] + bv[k])
  gemm_mfma<<<ggrid1, blk, 0, stream>>>(P_bf, (size_t)0, feats_bf, bt_h1, b0, bv, h1_bf);
  // agg[k] = propagate(h1[k])
  spmm_bf<3><<<sblocks, blk, 0, stream>>>(h1_bf, norm, rowptr, col, agg_bf);
  // out = (1/3) * sum_k relu(agg[k] @ w[k] + feats @ v[k] + bw[k] + bv[k])
  gemm_out_fused<<<ggrid2, blk, 0, stream>>>(agg_bf, feats_bf, bt_out, bw, bv, out);
}

// Round 7
// 353.714 us; speedup vs baseline: 2.6229x; 1.0215x over previous
//
#include <hip/hip_runtime.h>

#define N_NODES 50000
#define N_EDGES 800000
#define D 128
#define PLANE ((size_t)N_NODES * D)
#define NCHUNK ((N_NODES + 255) / 256)  // 196

typedef float f32x4 __attribute__((ext_vector_type(4)));
typedef float f32x2 __attribute__((ext_vector_type(2)));
typedef short bf16x8 __attribute__((ext_vector_type(8)));

__device__ __forceinline__ unsigned short f2bf(float x) {
  unsigned int u = __float_as_uint(x);
  u += 0x7FFFu + ((u >> 16) & 1u);  // RNE
  return (unsigned short)(u >> 16);
}
__device__ __forceinline__ float bf2f(unsigned short h) {
  return __uint_as_float((unsigned int)h << 16);
}
// HW OCP e4m3 converts (gfx950)
__device__ __forceinline__ unsigned char f32_to_fp8(float x) {
  int p = __builtin_amdgcn_cvt_pk_fp8_f32(x, x, 0, false);
  return (unsigned char)(p & 0xFF);
}
__device__ __forceinline__ void fp8x4_to_f32(int pk, float* f) {
  f32x2 lo = __builtin_amdgcn_cvt_pk_f32_fp8(pk, false);
  f32x2 hi = __builtin_amdgcn_cvt_pk_f32_fp8(pk, true);
  f[0] = lo.x; f[1] = lo.y; f[2] = hi.x; f[3] = hi.y;
}

// ---------------- CSR build ----------------

__global__ __launch_bounds__(256) void scan_local(const int* __restrict__ cnt,
                                                  int* __restrict__ local,
                                                  int* __restrict__ partial) {
  __shared__ int s[256];
  int t = threadIdx.x;
  int i = blockIdx.x * 256 + t;
  int v = (i < N_NODES) ? cnt[i] : 0;
  s[t] = v;
  __syncthreads();
  for (int off = 1; off < 256; off <<= 1) {
    int tmp = (t >= off) ? s[t - off] : 0;
    __syncthreads();
    s[t] += tmp;
    __syncthreads();
  }
  if (i < N_NODES) local[i] = s[t] - v;
  if (t == 255) partial[blockIdx.x] = s[255];
}

__global__ __launch_bounds__(256) void scan_chunks(const int* __restrict__ partial,
                                                   int* __restrict__ chunk_off,
                                                   int* __restrict__ rowptr) {
  __shared__ int s[256];
  int t = threadIdx.x;
  int v = (t < NCHUNK) ? partial[t] : 0;
  s[t] = v;
  __syncthreads();
  for (int off = 1; off < 256; off <<= 1) {
    int tmp = (t >= off) ? s[t - off] : 0;
    __syncthreads();
    s[t] += tmp;
    __syncthreads();
  }
  if (t < NCHUNK) chunk_off[t] = s[t] - v;
  if (t == 255) rowptr[N_NODES] = s[255];
}

__global__ __launch_bounds__(256) void finalize_rows(const int* __restrict__ cnt,
                                                     const int* __restrict__ local,
                                                     const int* __restrict__ chunk_off,
                                                     int* __restrict__ rowptr,
                                                     int* __restrict__ cursor,
                                                     float* __restrict__ norm) {
  int i = blockIdx.x * 256 + threadIdx.x;
  if (i < N_NODES) {
    int r = local[i] + chunk_off[blockIdx.x];
    rowptr[i] = r;
    cursor[i] = r;
    int d = cnt[i];
    if (d < 1) d = 1;
    norm[i] = rsqrtf((float)d);
  }
}

__global__ __launch_bounds__(256) void fill_csr(const int* __restrict__ src,
                                                const int* __restrict__ dst,
                                                int* __restrict__ cursor,
                                                int* __restrict__ col) {
  int e = blockIdx.x * blockDim.x + threadIdx.x;
  if (e < N_EDGES) {
    int pos = atomicAdd(&cursor[dst[e]], 1);
    col[pos] = src[e];
  }
}

// ---------------- fused prep: feats->bf16 + feats->fp8 + weight transposes + deg count ----

#define CONV_THREADS ((int)(PLANE / 4))            // 1,600,000
#define WT_THREADS (2 * 3 * 128 * 256)             // 196,608
#define PREP_TOTAL (CONV_THREADS + WT_THREADS + N_EDGES)

__global__ __launch_bounds__(256) void prep_all(const float* __restrict__ feats,
                                                const float* __restrict__ w0,
                                                const float* __restrict__ w,
                                                const float* __restrict__ v,
                                                const int* __restrict__ dst,
                                                unsigned short* __restrict__ feats_bf,
                                                unsigned char* __restrict__ feats_fp8,
                                                unsigned short* __restrict__ bt_h1,
                                                unsigned short* __restrict__ bt_out,
                                                int* __restrict__ cnt) {
  int idx = blockIdx.x * 256 + threadIdx.x;
  if (idx < CONV_THREADS) {
    float4 x = ((const float4*)feats)[idx];
    ushort4 o;
    o.x = f2bf(x.x);
    o.y = f2bf(x.y);
    o.z = f2bf(x.z);
    o.w = f2bf(x.w);
    ((ushort4*)feats_bf)[idx] = o;
    int p = __builtin_amdgcn_cvt_pk_fp8_f32(x.x, x.y, 0, false);
    p = __builtin_amdgcn_cvt_pk_fp8_f32(x.z, x.w, p, true);
    ((int*)feats_fp8)[idx] = p;
    return;
  }
  idx -= CONV_THREADS;
  if (idx < WT_THREADS) {
    int buf = idx / 98304;
    int rem = idx - buf * 98304;
    int stack = rem / 32768;
    int rem2 = rem & 32767;
    int n = rem2 >> 8;
    int k = rem2 & 255;
    const float* srcm;
    int kk;
    if (k < 128) {
      srcm = (buf == 0) ? w0 : w;
      kk = k;
    } else {
      srcm = v;
      kk = k - 128;
    }
    float val = srcm[(size_t)stack * 16384 + (size_t)kk * 128 + n];
    unsigned short* dstb = (buf == 0) ? bt_h1 : bt_out;
    dstb[(size_t)stack * 32768 + (size_t)n * 256 + k] = f2bf(val);
    return;
  }
  idx -= WT_THREADS;
  if (idx < N_EDGES) atomicAdd(&cnt[dst[idx]], 1);
}

// ---------------- pull-mode SpMM over fp8 planes, 8 edges/iter, 16 B/lane ----------------
// wave = one dst row. lane: sub = lane>>3 (edge slot 0..7), c8 = lane&7
// (16-feat chunk). One int4 load per plane per iter = 16 fp8 = 16 feats.
// 3-level butterfly (xor 8/16/32) combines the 8 edge slots. Output bf16.

template <int NK>
__global__ __launch_bounds__(256) void spmm_fp8(const unsigned char* __restrict__ h,
                                                const float* __restrict__ norm,
                                                const int* __restrict__ rowptr,
                                                const int* __restrict__ col,
                                                unsigned short* __restrict__ out) {
  int row = blockIdx.x * 4 + (threadIdx.x >> 6);
  if (row >= N_NODES) return;
  int lane = threadIdx.x & 63;
  int sub = lane >> 3;
  int c8 = lane & 7;
  int beg = rowptr[row], end = rowptr[row + 1];

  float acc[NK][16];
#pragma unroll
  for (int m = 0; m < NK; ++m)
#pragma unroll
    for (int j = 0; j < 16; ++j) acc[m][j] = 0.f;

#pragma unroll 2
  for (int e = beg; e < end; e += 8) {
    int eidx = e + sub;
    bool valid = eidx < end;
    int s = valid ? col[eidx] : 0;
    float wgt = valid ? norm[s] : 0.f;
    const unsigned char* hp = h + (size_t)s * D + c8 * 16;
#pragma unroll
    for (int m = 0; m < NK; ++m) {
      int4 pkt = *(const int4*)(hp + m * PLANE);
      float f[16];
      fp8x4_to_f32(pkt.x, f + 0);
      fp8x4_to_f32(pkt.y, f + 4);
      fp8x4_to_f32(pkt.z, f + 8);
      fp8x4_to_f32(pkt.w, f + 12);
#pragma unroll
      for (int j = 0; j < 16; ++j) acc[m][j] = fmaf(wgt, f[j], acc[m][j]);
    }
  }

#pragma unroll
  for (int m = 0; m < NK; ++m)
#pragma unroll
    for (int j = 0; j < 16; ++j) {
      float vv = acc[m][j];
      vv += __shfl_xor(vv, 8);
      vv += __shfl_xor(vv, 16);
      vv += __shfl_xor(vv, 32);
      acc[m][j] = vv;
    }

  if (sub == 0) {
    float nd = norm[row];
#pragma unroll
    for (int m = 0; m < NK; ++m) {
      bf16x8 o0, o1;
#pragma unroll
      for (int j = 0; j < 8; ++j) {
        o0[j] = (short)f2bf(acc[m][j] * nd);
        o1[j] = (short)f2bf(acc[m][j + 8] * nd);
      }
      unsigned short* op = out + m * PLANE + (size_t)row * D + c8 * 16;
      *(bf16x8*)op = o0;
      *(bf16x8*)(op + 8) = o1;
    }
  }
}

// ---------------- MFMA GEMM ----------------
// Block: 256 threads = 4 waves, M-tile 128 rows, N-tile 64 cols (blockIdx.y).
// B half-tile (64n x 256k bf16 = 32 KB) in LDS, XOR-swizzled (2-way max).
// Stacks looped in-kernel; shared-A fragments hoisted into registers.
// Fragments (m89/m120-verified): A[m=lane&15][k=(lane>>4)*8+j];
// B-frag = Bt[n=lane&15][k..]; C/D col=lane&15, row=(lane>>4)*4+reg.

__device__ __forceinline__ void stage_B64(unsigned short (*Bs)[256],
                                          const unsigned short* __restrict__ Btg,
                                          int nh, int tid) {
#pragma unroll
  for (int i = 0; i < 8; ++i) {
    int t = tid + i * 256;       // 0..2047 16B-chunks
    int n = t >> 5;              // 0..63
    int kc = t & 31;
    int kcs = kc ^ (n & 31);     // swizzle
    *(bf16x8*)&Bs[n][kcs * 8] = *(const bf16x8*)(Btg + (size_t)(nh + n) * 256 + kc * 8);
  }
}

__device__ __forceinline__ bf16x8 read_B64(const unsigned short (*Bs)[256], int n,
                                           int chunk) {
  return *(const bf16x8*)&Bs[n][(chunk ^ (n & 31)) * 8];
}

// layer-1: h1_fp8[stk] = relu(P @ w0[stk] + feats @ v[stk] + b0 + bv)
// P and feats shared across stacks -> A-frags loaded ONCE.
__global__ __launch_bounds__(256) void gemm_h1_fused(
    const unsigned short* __restrict__ P,
    const unsigned short* __restrict__ feats_bf,
    const unsigned short* __restrict__ Bt,
    const float* __restrict__ b0, const float* __restrict__ bv,
    unsigned char* __restrict__ h1_fp8) {
  __shared__ unsigned short Bs[64][256];
  int nh = blockIdx.y * 64;

  int tid = threadIdx.x;
  int lane = tid & 63;
  int wv = tid >> 6;
  int ln15 = lane & 15;
  int g = lane >> 4;

  int m0 = blockIdx.x * 128 + wv * 32;
  int r0 = m0 + ln15;
  int r1 = m0 + 16 + ln15;
  if (r0 >= N_NODES) r0 = N_NODES - 1;
  if (r1 >= N_NODES) r1 = N_NODES - 1;

  bf16x8 a0[8], a1[8];  // s=0..3 from P (k<128), s=4..7 from feats (k>=128)
#pragma unroll
  for (int s = 0; s < 4; ++s) {
    a0[s] = *(const bf16x8*)(P + (size_t)r0 * 128 + g * 8 + s * 32);
    a1[s] = *(const bf16x8*)(P + (size_t)r1 * 128 + g * 8 + s * 32);
    a0[s + 4] = *(const bf16x8*)(feats_bf + (size_t)r0 * 128 + g * 8 + s * 32);
    a1[s + 4] = *(const bf16x8*)(feats_bf + (size_t)r1 * 128 + g * 8 + s * 32);
  }

  for (int stk = 0; stk < 3; ++stk) {
    if (stk) __syncthreads();
    stage_B64(Bs, Bt + (size_t)stk * 32768, nh, tid);
    __syncthreads();

    f32x4 acc0[4], acc1[4];
#pragma unroll
    for (int nt = 0; nt < 4; ++nt) { acc0[nt] = (f32x4)(0.f); acc1[nt] = (f32x4)(0.f); }

#pragma unroll
    for (int s = 0; s < 8; ++s) {
#pragma unroll
      for (int nt = 0; nt < 4; ++nt) {
        bf16x8 bfr = read_B64(Bs, nt * 16 + ln15, s * 4 + g);
        acc0[nt] = __builtin_amdgcn_mfma_f32_16x16x32_bf16(a0[s], bfr, acc0[nt], 0, 0, 0);
        acc1[nt] = __builtin_amdgcn_mfma_f32_16x16x32_bf16(a1[s], bfr, acc1[nt], 0, 0, 0);
      }
    }

    unsigned char* outp = h1_fp8 + (size_t)stk * PLANE;
#pragma unroll
    for (int nt = 0; nt < 4; ++nt) {
      int colj = nh + nt * 16 + ln15;
      float bsum = b0[stk * 128 + colj] + bv[stk * 128 + colj];
#pragma unroll
      for (int r = 0; r < 4; ++r) {
        int mA = m0 + g * 4 + r;
        int mB = m0 + 16 + g * 4 + r;
        if (mA < N_NODES) {
          float x = acc0[nt][r] + bsum;
          outp[(size_t)mA * 128 + colj] = f32_to_fp8(x > 0.f ? x : 0.f);
        }
        if (mB < N_NODES) {
          float x = acc1[nt][r] + bsum;
          outp[(size_t)mB * 128 + colj] = f32_to_fp8(x > 0.f ? x : 0.f);
        }
      }
    }
  }
}

// layer-2 fused: out = (1/3) * sum_stk relu(agg[stk] @ w[stk] + feats @ v[stk] + bw + bv)
// feats fragments hoisted (shared across stacks); agg fragments per stack.
__global__ __launch_bounds__(256) void gemm_out_fused(
    const unsigned short* __restrict__ agg,
    const unsigned short* __restrict__ feats_bf,
    const unsigned short* __restrict__ Bt,
    const float* __restrict__ bwp, const float* __restrict__ bvp,
    float* __restrict__ outp) {
  __shared__ unsigned short Bs[64][256];
  int nh = blockIdx.y * 64;

  int tid = threadIdx.x;
  int lane = tid & 63;
  int wv = tid >> 6;
  int ln15 = lane & 15;
  int g = lane >> 4;

  int m0 = blockIdx.x * 128 + wv * 32;
  int r0 = m0 + ln15;
  int r1 = m0 + 16 + ln15;
  if (r0 >= N_NODES) r0 = N_NODES - 1;
  if (r1 >= N_NODES) r1 = N_NODES - 1;

  bf16x8 f0[4], f1[4];  // feats frags (k=128..255 phase)
#pragma unroll
  for (int s = 0; s < 4; ++s) {
    f0[s] = *(const bf16x8*)(feats_bf + (size_t)r0 * 128 + g * 8 + s * 32);
    f1[s] = *(const bf16x8*)(feats_bf + (size_t)r1 * 128 + g * 8 + s * 32);
  }

  f32x4 sum0[4], sum1[4];
#pragma unroll
  for (int nt = 0; nt < 4; ++nt) { sum0[nt] = (f32x4)(0.f); sum1[nt] = (f32x4)(0.f); }

  for (int stk = 0; stk < 3; ++stk) {
    if (stk) __syncthreads();
    stage_B64(Bs, Bt + (size_t)stk * 32768, nh, tid);
    __syncthreads();

    const unsigned short* A1 = agg + (size_t)stk * PLANE;
    bf16x8 g0[4], g1[4];
#pragma unroll
    for (int s = 0; s < 4; ++s) {
      g0[s] = *(const bf16x8*)(A1 + (size_t)r0 * 128 + g * 8 + s * 32);
      g1[s] = *(const bf16x8*)(A1 + (size_t)r1 * 128 + g * 8 + s * 32);
    }

    f32x4 acc0[4], acc1[4];
#pragma unroll
    for (int nt = 0; nt < 4; ++nt) { acc0[nt] = (f32x4)(0.f); acc1[nt] = (f32x4)(0.f); }

#pragma unroll
    for (int s = 0; s < 8; ++s) {
      bf16x8 af0 = (s < 4) ? g0[s & 3] : f0[s & 3];
      bf16x8 af1 = (s < 4) ? g1[s & 3] : f1[s & 3];
#pragma unroll
      for (int nt = 0; nt < 4; ++nt) {
        bf16x8 bfr = read_B64(Bs, nt * 16 + ln15, s * 4 + g);
        acc0[nt] = __builtin_amdgcn_mfma_f32_16x16x32_bf16(af0, bfr, acc0[nt], 0, 0, 0);
        acc1[nt] = __builtin_amdgcn_mfma_f32_16x16x32_bf16(af1, bfr, acc1[nt], 0, 0, 0);
      }
    }

#pragma unroll
    for (int nt = 0; nt < 4; ++nt) {
      int colj = nh + nt * 16 + ln15;
      float bsum = bwp[stk * 128 + colj] + bvp[stk * 128 + colj];
#pragma unroll
      for (int r = 0; r < 4; ++r) {
        float x0 = acc0[nt][r] + bsum;
        float x1 = acc1[nt][r] + bsum;
        sum0[nt][r] += (x0 > 0.f ? x0 : 0.f);
        sum1[nt][r] += (x1 > 0.f ? x1 : 0.f);
      }
    }
  }

  const float sc = 1.0f / 3.0f;
#pragma unroll
  for (int nt = 0; nt < 4; ++nt) {
    int colj = nh + nt * 16 + ln15;
#pragma unroll
    for (int r = 0; r < 4; ++r) {
      int mA = m0 + g * 4 + r;
      int mB = m0 + 16 + g * 4 + r;
      if (mA < N_NODES) outp[(size_t)mA * 128 + colj] = sum0[nt][r] * sc;
      if (mB < N_NODES) outp[(size_t)mB * 128 + colj] = sum1[nt][r] * sc;
    }
  }
}

// ---------------- launcher ----------------

extern "C" void kernel_launch(void* const* d_in, const int* in_sizes, int n_in,
                              void* d_out, int out_size, void* d_ws, size_t ws_size,
                              hipStream_t stream) {
  const float* feats = (const float*)d_in[0];
  const int* src = (const int*)d_in[1];
  const int* dst = (const int*)d_in[2];
  const float* w0 = (const float*)d_in[3];
  const float* b0 = (const float*)d_in[4];
  const float* w = (const float*)d_in[5];
  const float* bw = (const float*)d_in[6];
  const float* v = (const float*)d_in[7];
  const float* bv = (const float*)d_in[8];
  float* out = (float*)d_out;

  char* ws = (char*)d_ws;
  size_t off = 0;
  auto alloc = [&](size_t bytes) {
    void* p = ws + off;
    off += (bytes + 255) & ~(size_t)255;
    return p;
  };
  int* cnt = (int*)alloc(N_NODES * 4);
  int* local = (int*)alloc(N_NODES * 4);
  int* partial = (int*)alloc(NCHUNK * 4);
  int* chunk_off = (int*)alloc(NCHUNK * 4);
  float* norm = (float*)alloc(N_NODES * 4);
  int* rowptr = (int*)alloc((N_NODES + 1) * 4);
  int* cursor = (int*)alloc(N_NODES * 4);
  int* col = (int*)alloc(N_EDGES * 4);
  unsigned short* bt_h1 = (unsigned short*)alloc(3 * 32768 * 2);
  unsigned short* bt_out = (unsigned short*)alloc(3 * 32768 * 2);

  size_t pb = PLANE * 2;  // bf16 plane bytes
  unsigned short* feats_bf = (unsigned short*)alloc(pb);
  unsigned char* feats_fp8 = (unsigned char*)alloc(PLANE);
  unsigned short* P_bf = (unsigned short*)alloc(pb);
  unsigned char* h1_fp8 = (unsigned char*)alloc(3 * PLANE);
  unsigned short* agg_bf = (unsigned short*)alloc(3 * pb);

  hipMemsetAsync(cnt, 0, N_NODES * 4, stream);

  dim3 blk(256);
  // prep: feats->bf16+fp8, weight transposes, degree count (fused)
  prep_all<<<(PREP_TOTAL + 255) / 256, blk, 0, stream>>>(feats, w0, w, v, dst, feats_bf,
                                                         feats_fp8, bt_h1, bt_out, cnt);
  scan_local<<<NCHUNK, blk, 0, stream>>>(cnt, local, partial);
  scan_chunks<<<1, blk, 0, stream>>>(partial, chunk_off, rowptr);
  finalize_rows<<<NCHUNK, blk, 0, stream>>>(cnt, local, chunk_off, rowptr, cursor, norm);
  fill_csr<<<(N_EDGES + 255) / 256, blk, 0, stream>>>(src, dst, cursor, col);

  int sblocks = (N_NODES + 3) / 4;
  int mblocks = (N_NODES + 127) / 128;
  dim3 ggrid(mblocks, 2);  // x: M-tile, y: N-half (stacks looped in-kernel)

  // P = propagate(feats)   (shared across stacks; fp8 gather -> bf16 out)
  spmm_fp8<1><<<sblocks, blk, 0, stream>>>(feats_fp8, norm, rowptr, col, P_bf);
  // h1[k] = relu(P @ w0[k] + feats @ v[k] + b0[k] + bv[k])  -> fp8 planes
  gemm_h1_fused<<<ggrid, blk, 0, stream>>>(P_bf, feats_bf, bt_h1, b0, bv, h1_fp8);
  // agg[k] = propagate(h1[k])   (fp8 gather -> bf16 out)
  spmm_fp8<3><<<sblocks, blk, 0, stream>>>(h1_fp8, norm, rowptr, col, agg_bf);
  // out = (1/3) * sum_k relu(agg[k] @ w[k] + feats @ v[k] + bw[k] + bv[k])
  gemm_out_fused<<<ggrid, blk, 0, stream>>>(agg_bf, feats_bf, bt_out, bw, bv, out);
}